// Round 6
// baseline (853.532 us; speedup 1.0000x reference)
//
#include <hip/hip_runtime.h>

typedef __attribute__((ext_vector_type(8))) unsigned short ushort8;
typedef __attribute__((ext_vector_type(4))) float f32x4;
typedef __attribute__((ext_vector_type(8))) __bf16 bf16x8;
typedef unsigned short u16;

__device__ inline unsigned short f2bf(float f) {
  unsigned u = __float_as_uint(f);
  unsigned r = (u + 0x7fffu + ((u >> 16) & 1u)) >> 16;
  return (unsigned short)r;
}
__device__ inline float bf2f(unsigned short h) {
  return __uint_as_float(((unsigned)h) << 16);
}

__device__ __forceinline__ void gload_lds16(const void* g, void* l) {
  __builtin_amdgcn_global_load_lds(
      (const __attribute__((address_space(1))) void*)g,
      (__attribute__((address_space(3))) void*)l, 16, 0, 0);
}

// block-id decomposition: XCD swizzle + grouped (8 by-rows) order
__device__ __forceinline__ void decomp_bid(int nbx, int nby, int& z, int& bx, int& by) {
  int bid = blockIdx.x;
  const int nwg = gridDim.x;
  const int q8 = nwg >> 3, r8 = nwg & 7;
  const int xcd = bid & 7, i = bid >> 3;
  bid = (xcd < r8 ? xcd * (q8 + 1) : r8 * (q8 + 1) + (xcd - r8) * q8) + i;
  const int nbb = nbx * nby;
  z = bid / nbb;
  int rem = bid - z * nbb;
  if ((nby & 7) == 0) {
    const int chunk = nbx << 3;
    const int c = rem / chunk, w = rem - c * chunk;
    bx = w >> 3;
    by = (c << 3) + (w & 7);
  } else {
    by = rem / nbx;
    bx = rem - by * nbx;
  }
}

// ---------------------------------------------------------------------------
// gemm8p: 256x256 tile, BK=64, 8-phase m201-style schedule, 8 waves (2Mx4N),
// per-wave 128x64 output. LDS 128 KiB = 2 buf x {A0,A1,B0,B1} 16KB halves.
// Counted vmcnt(4) at phases 4/8 only. Requires M%256==0, N%256==0,
// K%128==0, K>=256.
// ---------------------------------------------------------------------------
__global__ __launch_bounds__(512, 2) void gemm8p(
    const u16* __restrict__ A, long lda, long sAo, long sAi,
    const u16* __restrict__ B, long ldb, long sBo, long sBi,
    void* __restrict__ C, long ldc, long sCo, long sCi,
    const float* __restrict__ bias, const float* __restrict__ resid, long ldr,
    int M, int N, int K, int nbx, int Hdiv, int outF32)
{
  __shared__ __align__(128) char smem[131072];
  const int tid = threadIdx.x;
  const int lane = tid & 63, wave = tid >> 6;
  const int wr = wave >> 2, wc = wave & 3;

  int z, bx, by;
  decomp_bid(nbx, M >> 8, z, bx, by);
  const int m0 = by << 8, n0 = bx << 8;
  const int zb = z / Hdiv, zh = z - zb * Hdiv;
  const u16* Ab = A + (long)zb * sAo + (long)zh * sAi;
  const u16* Bb = B + (long)zb * sBo + (long)zh * sBi;

  // staging addressing (proven zero-conflict granule swizzle)
  const int srow = tid >> 3;
  const int g8 = ((tid & 7) ^ (srow & 7)) * 8;
  const long aoff0 = (long)(m0 + srow) * lda + g8;
  const long boff0 = (long)(n0 + srow) * ldb + g8;
  const int ldst = tid * 16;

  // fragment-read addressing
  const int r15 = lane & 15, kq = lane >> 4;
  const int offK0 = (kq ^ (lane & 7)) * 16;
  const int offK1 = ((4 + kq) ^ (lane & 7)) * 16;
  const int abase = wr * 16384;            // this wave's A-half
  const int bbase = 32768 + (wc >> 1) * 16384;  // this wave's B-half
  const int bcol = (wc & 1) * 64;          // col offset inside B-half

  // stage one half-tile (16KB = 2 x 8KB loads)
  auto stgA = [&](int cb, int h, long kk) {
    gload_lds16(Ab + aoff0 + (long)(h * 128) * lda + kk, smem + cb + h * 16384 + ldst);
    gload_lds16(Ab + aoff0 + (long)(h * 128 + 64) * lda + kk, smem + cb + h * 16384 + 8192 + ldst);
  };
  auto stgB = [&](int cb, int h, long kk) {
    gload_lds16(Bb + boff0 + (long)(h * 128) * ldb + kk, smem + cb + 32768 + h * 16384 + ldst);
    gload_lds16(Bb + boff0 + (long)(h * 128 + 64) * ldb + kk, smem + cb + 32768 + h * 16384 + 8192 + ldst);
  };

  // prologue: buf0 <- K-tile 0 (all), buf1.B <- K-tile 1
  stgA(0, 0, 0); stgA(0, 1, 0); stgB(0, 0, 0); stgB(0, 1, 0);
  stgB(65536, 0, 64); stgB(65536, 1, 64);
  asm volatile("s_waitcnt vmcnt(4)" ::: "memory");
  __builtin_amdgcn_s_barrier();

  f32x4 acc[8][4] = {};
  const int nIter = K >> 7;   // 2 K-tiles (of 64) per iteration

#define WVC(NL)                                                          \
  do {                                                                   \
    if (NL) asm volatile("s_waitcnt vmcnt(4)" ::: "memory");             \
    else    asm volatile("s_waitcnt vmcnt(0)" ::: "memory");             \
  } while (0)

#define PHASE(CB, P, PREBAR, ...)                                        \
  {                                                                      \
    bf16x8 af[2][2];                                                     \
    _Pragma("unroll") for (int i2 = 0; i2 < 2; ++i2) {                   \
      const int ra = (CB) + abase + ((P) * 32 + i2 * 16 + r15) * 128;    \
      af[i2][0] = *(const bf16x8*)(smem + ra + offK0);                   \
      af[i2][1] = *(const bf16x8*)(smem + ra + offK1);                   \
    }                                                                    \
    if ((P) == 0) {                                                      \
      _Pragma("unroll") for (int j = 0; j < 4; ++j) {                    \
        const int rb2 = (CB) + bbase + (bcol + j * 16 + r15) * 128;      \
        bfr[j][0] = *(const bf16x8*)(smem + rb2 + offK0);                \
        bfr[j][1] = *(const bf16x8*)(smem + rb2 + offK1);                \
      }                                                                  \
    }                                                                    \
    __VA_ARGS__;                                                         \
    __builtin_amdgcn_s_barrier();                                        \
    __builtin_amdgcn_s_setprio(1);                                       \
    _Pragma("unroll") for (int kk = 0; kk < 2; ++kk)                     \
      _Pragma("unroll") for (int i2 = 0; i2 < 2; ++i2)                   \
        _Pragma("unroll") for (int j = 0; j < 4; ++j)                    \
          acc[(P) * 2 + i2][j] = __builtin_amdgcn_mfma_f32_16x16x32_bf16(\
              af[i2][kk], bfr[j][kk], acc[(P) * 2 + i2][j], 0, 0, 0);    \
    __builtin_amdgcn_s_setprio(0);                                       \
    PREBAR;                                                              \
    __builtin_amdgcn_s_barrier();                                        \
  }

  for (int it = 0; it < nIter; ++it) {
    const long k0 = (long)it << 7;
    const bool nl = (it + 1 < nIter);
    bf16x8 bfr[4][2];
    // K-tile 2it (buf0), phases 1-4
    PHASE(0, 0, (void)0, stgA(65536, 0, k0 + 64); stgA(65536, 1, k0 + 64))
    PHASE(0, 1, (void)0, if (nl) stgB(0, 0, k0 + 128))
    PHASE(0, 2, (void)0, if (nl) stgB(0, 1, k0 + 128))
    PHASE(0, 3, WVC(nl), (void)0)
    // K-tile 2it+1 (buf1), phases 5-8
    PHASE(65536, 0, (void)0, if (nl) stgA(0, 0, k0 + 128))
    PHASE(65536, 1, (void)0, if (nl) stgA(0, 1, k0 + 128))
    PHASE(65536, 2, (void)0, if (nl) stgB(65536, 0, k0 + 192))
    PHASE(65536, 3, WVC(nl), if (nl) stgB(65536, 1, k0 + 192))
  }
#undef PHASE
#undef WVC

  // epilogue
  const long cbase = (long)zb * sCo + (long)zh * sCi;
  const int rb = (lane >> 4) * 4;
#pragma unroll
  for (int i = 0; i < 8; ++i) {
#pragma unroll
    for (int j = 0; j < 4; ++j) {
      const int gcol = n0 + wc * 64 + j * 16 + r15;
      if (gcol >= N) continue;
      const float bv = bias ? bias[gcol] : 0.f;
#pragma unroll
      for (int tt = 0; tt < 4; ++tt) {
        const int grow = m0 + wr * 128 + i * 16 + rb + tt;
        float val = acc[i][j][tt] + bv;
        if (resid) val += resid[(long)grow * ldr + gcol];
        const long cidx = cbase + (long)grow * ldc + gcol;
        if (outF32) ((float*)C)[cidx] = val;
        else ((u16*)C)[cidx] = f2bf(val);
      }
    }
  }
}

// ---------------------------------------------------------------------------
// gemm64: 128x128 tile, BK=64, 2 LDS bufs (64 KiB), 8 waves, 2 blocks/CU.
// ---------------------------------------------------------------------------
__global__ __launch_bounds__(512, 4) void gemm64(
    const u16* __restrict__ A, long lda, long sAo, long sAi,
    const u16* __restrict__ B, long ldb, long sBo, long sBi,
    void* __restrict__ C, long ldc, long sCo, long sCi,
    const float* __restrict__ bias, const float* __restrict__ resid, long ldr,
    int M, int N, int K, int nbx, int Hdiv, float alpha, int outF32)
{
  __shared__ __align__(128) char smem[65536];
  const int tid = threadIdx.x;
  const int lane = tid & 63, wave = tid >> 6;

  int z, bx, by;
  decomp_bid(nbx, M >> 7, z, bx, by);
  const int m0 = by << 7, n0 = bx << 7;
  const int zb = z / Hdiv, zh = z - zb * Hdiv;
  const u16* Ab = A + (long)zb * sAo + (long)zh * sAi;
  const u16* Bb = B + (long)zb * sBo + (long)zh * sBi;

  const int srow = tid >> 3;
  const int g8 = ((tid & 7) ^ (srow & 7)) * 8;
  long aoff[2], boff[2];
#pragma unroll
  for (int i = 0; i < 2; ++i) {
    aoff[i] = (long)(m0 + i * 64 + srow) * lda + g8;
    boff[i] = (long)(n0 + i * 64 + srow) * ldb + g8;
  }
  const int ldst = tid * 16;

  const int wm = (wave >> 2) * 64, wn = (wave & 3) * 32;
  const int r15 = lane & 15, kq = lane >> 4;
  const int offK0 = (kq ^ (lane & 7)) * 16;
  const int offK1 = ((4 + kq) ^ (lane & 7)) * 16;

  const int nt = K >> 6;

#define STAGE64(bufofs, k0)                                                       \
  do {                                                                            \
    _Pragma("unroll") for (int i = 0; i < 2; ++i)                                 \
        gload_lds16(Ab + aoff[i] + (k0), smem + (bufofs) + i * 8192 + ldst);      \
    _Pragma("unroll") for (int i = 0; i < 2; ++i)                                 \
        gload_lds16(Bb + boff[i] + (k0), smem + (bufofs) + 16384 + i * 8192 + ldst); \
  } while (0)

  STAGE64(0, 0);
  STAGE64(32768, 64);

  f32x4 acc[4][2] = {};

  for (int t = 0; t < nt; ++t) {
    const int cbuf = (t & 1) << 15;
    if (t < nt - 1) asm volatile("s_waitcnt vmcnt(4)" ::: "memory");
    else            asm volatile("s_waitcnt vmcnt(0)" ::: "memory");
    __builtin_amdgcn_s_barrier();

    bf16x8 bfr[2][2];
#pragma unroll
    for (int q = 0; q < 2; ++q) {
      if (q == 0) {
#pragma unroll
        for (int j = 0; j < 2; ++j) {
          const int bb = cbuf + 16384 + (wn + j * 16 + r15) * 128;
          bfr[j][0] = *(const bf16x8*)(smem + bb + offK0);
          bfr[j][1] = *(const bf16x8*)(smem + bb + offK1);
        }
      }
      bf16x8 af[2][2];
#pragma unroll
      for (int i2 = 0; i2 < 2; ++i2) {
        const int ab = cbuf + (wm + (q * 2 + i2) * 16 + r15) * 128;
        af[i2][0] = *(const bf16x8*)(smem + ab + offK0);
        af[i2][1] = *(const bf16x8*)(smem + ab + offK1);
      }
      __builtin_amdgcn_s_setprio(1);
#pragma unroll
      for (int kk = 0; kk < 2; ++kk)
#pragma unroll
        for (int i2 = 0; i2 < 2; ++i2)
#pragma unroll
          for (int j = 0; j < 2; ++j)
            acc[q * 2 + i2][j] = __builtin_amdgcn_mfma_f32_16x16x32_bf16(
                af[i2][kk], bfr[j][kk], acc[q * 2 + i2][j], 0, 0, 0);
      __builtin_amdgcn_s_setprio(0);
      __builtin_amdgcn_s_barrier();
    }
    if (t + 2 < nt) STAGE64(cbuf, (long)(t + 2) * 64);
  }
#undef STAGE64

  const long cbase = (long)zb * sCo + (long)zh * sCi;
  const int rb = (lane >> 4) * 4;
#pragma unroll
  for (int i = 0; i < 4; ++i) {
#pragma unroll
    for (int j = 0; j < 2; ++j) {
      const int gcol = n0 + wn + j * 16 + r15;
      if (gcol >= N) continue;
      const float bv = bias ? bias[gcol] : 0.f;
#pragma unroll
      for (int tt = 0; tt < 4; ++tt) {
        const int grow = m0 + wm + i * 16 + rb + tt;
        float val = acc[i][j][tt] * alpha + bv;
        if (resid) val += resid[(long)grow * ldr + gcol];
        const long cidx = cbase + (long)grow * ldc + gcol;
        if (outF32) ((float*)C)[cidx] = val;
        else ((u16*)C)[cidx] = f2bf(val);
      }
    }
  }
}

// ---------------------------------------------------------------------------
// gemm32: 128x128 tile, BK=32, for K%32 shapes (K=160/96).
// ---------------------------------------------------------------------------
__global__ __launch_bounds__(512, 4) void gemm32(
    const u16* __restrict__ A, long lda, long sAo, long sAi,
    const u16* __restrict__ B, long ldb, long sBo, long sBi,
    void* __restrict__ C, long ldc, long sCo, long sCi,
    const float* __restrict__ bias, const float* __restrict__ resid, long ldr,
    int M, int N, int K, int nbx, int Hdiv, float alpha, int outF32)
{
  __shared__ __align__(128) char smem[32768];
  const int tid = threadIdx.x;
  const int lane = tid & 63, wave = tid >> 6;

  int z, bx, by;
  decomp_bid(nbx, M >> 7, z, bx, by);
  const int m0 = by << 7, n0 = bx << 7;
  const int zb = z / Hdiv, zh = z - zb * Hdiv;
  const u16* Ab = A + (long)zb * sAo + (long)zh * sAi;
  const u16* Bb = B + (long)zb * sBo + (long)zh * sBi;

  const int srow = tid >> 2;
  const int g8 = ((tid & 3) ^ ((tid >> 3) & 3)) * 8;
  const long aoff = (long)(m0 + srow) * lda + g8;
  const long boff = (long)(n0 + srow) * ldb + g8;
  const int ldst = tid * 16;

  const int wm = (wave >> 2) * 64, wn = (wave & 3) * 32;
  const int r15 = lane & 15, kq = lane >> 4;
  const int goff = (kq ^ ((r15 >> 1) & 3)) * 16;

  const int nt = K >> 5;

#define STAGE32(bufofs, k0)                                                \
  do {                                                                     \
    gload_lds16(Ab + aoff + (k0), smem + (bufofs) + ldst);                 \
    gload_lds16(Bb + boff + (k0), smem + (bufofs) + 8192 + ldst);          \
  } while (0)

  STAGE32(0, 0);
  STAGE32(16384, 32);

  f32x4 acc[4][2] = {};

  for (int t = 0; t < nt; ++t) {
    const int cbuf = (t & 1) << 14;
    if (t < nt - 1) asm volatile("s_waitcnt vmcnt(2)" ::: "memory");
    else            asm volatile("s_waitcnt vmcnt(0)" ::: "memory");
    __builtin_amdgcn_s_barrier();

    bf16x8 af[4], bfr[2];
#pragma unroll
    for (int i = 0; i < 4; ++i)
      af[i] = *(const bf16x8*)(smem + cbuf + (wm + i * 16 + r15) * 64 + goff);
#pragma unroll
    for (int j = 0; j < 2; ++j)
      bfr[j] = *(const bf16x8*)(smem + cbuf + 8192 + (wn + j * 16 + r15) * 64 + goff);

    __builtin_amdgcn_s_setprio(1);
#pragma unroll
    for (int i = 0; i < 4; ++i)
#pragma unroll
      for (int j = 0; j < 2; ++j)
        acc[i][j] = __builtin_amdgcn_mfma_f32_16x16x32_bf16(af[i], bfr[j], acc[i][j], 0, 0, 0);
    __builtin_amdgcn_s_setprio(0);
    __builtin_amdgcn_s_barrier();

    if (t + 2 < nt) STAGE32(cbuf, (long)(t + 2) * 32);
  }
#undef STAGE32

  const long cbase = (long)zb * sCo + (long)zh * sCi;
  const int rb = (lane >> 4) * 4;
#pragma unroll
  for (int i = 0; i < 4; ++i) {
#pragma unroll
    for (int j = 0; j < 2; ++j) {
      const int gcol = n0 + wn + j * 16 + r15;
      if (gcol >= N) continue;
      const float bv = bias ? bias[gcol] : 0.f;
#pragma unroll
      for (int tt = 0; tt < 4; ++tt) {
        const int grow = m0 + wm + i * 16 + rb + tt;
        float val = acc[i][j][tt] * alpha + bv;
        if (resid) val += resid[(long)grow * ldr + gcol];
        const long cidx = cbase + (long)grow * ldc + gcol;
        if (outF32) ((float*)C)[cidx] = val;
        else ((u16*)C)[cidx] = f2bf(val);
      }
    }
  }
}

// ---------------------------------------------------------------------------
// Legacy 128x128 NT GEMM (M=154 ctx KV only)
// ---------------------------------------------------------------------------
__global__ __launch_bounds__(256) void gemm_nt(
    const u16* __restrict__ A, long lda, long sAo, long sAi,
    const u16* __restrict__ B, long ldb, long sBo, long sBi,
    void* __restrict__ C, long ldc, long sCo, long sCi,
    const float* __restrict__ bias,
    const float* __restrict__ resid, long ldr,
    int M, int N, int K, int Hdiv, float alpha, int outF32)
{
  __shared__ u16 As[128 * 32];
  __shared__ u16 Bs[128 * 32];
  const int tid = threadIdx.x;
  const int z = blockIdx.z;
  const int zb = z / Hdiv, zh = z % Hdiv;
  const u16* Ab = A + (long)zb * sAo + (long)zh * sAi;
  const u16* Bb = B + (long)zb * sBo + (long)zh * sBi;
  const long cbase = (long)zb * sCo + (long)zh * sCi;
  const int m0 = blockIdx.y * 128, n0 = blockIdx.x * 128;
  const int lane = tid & 63, wave = tid >> 6;
  const int wm = (wave >> 1) * 64, wn = (wave & 1) * 64;
  const int r15 = lane & 15, kb = (lane >> 4) * 8;

  f32x4 acc[4][4] = {};

  for (int k0 = 0; k0 < K; k0 += 32) {
#pragma unroll
    for (int it = 0; it < 2; ++it) {
      const int c = tid + it * 256;
      const int row = c >> 2, ko = (c & 3) * 8;
      ushort8 va = {0, 0, 0, 0, 0, 0, 0, 0};
      const int gm = m0 + row;
      if (gm < M) va = *reinterpret_cast<const ushort8*>(Ab + (long)gm * lda + k0 + ko);
      *reinterpret_cast<ushort8*>(&As[row * 32 + ko]) = va;
      ushort8 vb = {0, 0, 0, 0, 0, 0, 0, 0};
      const int gn = n0 + row;
      if (gn < N) vb = *reinterpret_cast<const ushort8*>(Bb + (long)gn * ldb + k0 + ko);
      *reinterpret_cast<ushort8*>(&Bs[row * 32 + ko]) = vb;
    }
    __syncthreads();
    bf16x8 af[4], bfr[4];
#pragma unroll
    for (int i = 0; i < 4; ++i)
      af[i] = *reinterpret_cast<const bf16x8*>(&As[(wm + i * 16 + r15) * 32 + kb]);
#pragma unroll
    for (int j = 0; j < 4; ++j)
      bfr[j] = *reinterpret_cast<const bf16x8*>(&Bs[(wn + j * 16 + r15) * 32 + kb]);
#pragma unroll
    for (int i = 0; i < 4; ++i)
#pragma unroll
      for (int j = 0; j < 4; ++j)
        acc[i][j] = __builtin_amdgcn_mfma_f32_16x16x32_bf16(af[i], bfr[j], acc[i][j], 0, 0, 0);
    __syncthreads();
  }

  const int rb = (lane >> 4) * 4;
#pragma unroll
  for (int i = 0; i < 4; ++i) {
#pragma unroll
    for (int j = 0; j < 4; ++j) {
      const int gcol = n0 + wn + j * 16 + r15;
      if (gcol >= N) continue;
#pragma unroll
      for (int t = 0; t < 4; ++t) {
        const int grow = m0 + wm + i * 16 + rb + t;
        if (grow >= M) continue;
        float val = acc[i][j][t] * alpha;
        if (bias) val += bias[gcol];
        if (resid) val += resid[(long)grow * ldr + gcol];
        const long cidx = cbase + (long)grow * ldc + gcol;
        if (outF32) ((float*)C)[cidx] = val;
        else ((u16*)C)[cidx] = f2bf(val);
      }
    }
  }
}

// ---------------------------------------------------------------------------
__global__ void transpose_convert(const float* __restrict__ in,
                                  u16* __restrict__ out, int R, int C) {
  __shared__ float tile[32][33];
  const int c0 = blockIdx.x * 32, r0 = blockIdx.y * 32;
  const int tx = threadIdx.x, ty = threadIdx.y;
  for (int i = ty; i < 32; i += 8) {
    const int r = r0 + i, c = c0 + tx;
    tile[i][tx] = (r < R && c < C) ? in[(long)r * C + c] : 0.f;
  }
  __syncthreads();
  for (int i = ty; i < 32; i += 8) {
    const int c = c0 + i, r = r0 + tx;
    if (c < C && r < R) out[(long)c * R + r] = f2bf(tile[tx][i]);
  }
}

__global__ void convert_bf16(const float* __restrict__ in,
                             u16* __restrict__ out, long n) {
  const long i = (long)blockIdx.x * 256 + threadIdx.x;
  if (i < n) out[i] = f2bf(in[i]);
}

__global__ __launch_bounds__(256) void adaln_emb(
    const float* __restrict__ t1, const float* __restrict__ w1, const float* __restrict__ b1,
    const float* __restrict__ t2, const float* __restrict__ w2, const float* __restrict__ b2,
    const int* __restrict__ tstep, float* __restrict__ e1, float* __restrict__ e2)
{
  const int which = blockIdx.y;
  const float* tb = which ? t2 : t1;
  const float* w = which ? w2 : w1;
  const float* bb = which ? b2 : b1;
  float* out = which ? e2 : e1;
  const int t = tstep[0];
  __shared__ float sil[1280];
  const int tid = threadIdx.x;
  for (int i = tid; i < 1280; i += 256) {
    const float xv = tb[(long)t * 1280 + i];
    sil[i] = xv / (1.f + expf(-xv));
  }
  __syncthreads();
  const int j = blockIdx.x * 256 + tid;
  float acc = bb[j];
  for (int k = 0; k < 1280; ++k) acc += sil[k] * w[(long)k * 2560 + j];
  out[j] = acc;
}

__global__ __launch_bounds__(256) void ln_mod(
    const float* __restrict__ x, u16* __restrict__ out,
    const float* __restrict__ emb, const float* __restrict__ g,
    const float* __restrict__ bv, int affine)
{
  const long row = blockIdx.x;
  const float* xr = x + row * 1280;
  const int tid = threadIdx.x;
  float v[5], s = 0.f, s2 = 0.f;
#pragma unroll
  for (int i = 0; i < 5; ++i) {
    const float t = xr[tid + i * 256];
    v[i] = t; s += t; s2 += t * t;
  }
  __shared__ float rs_[4], rs2_[4], bc[2];
  for (int off = 32; off; off >>= 1) {
    s += __shfl_down(s, off, 64);
    s2 += __shfl_down(s2, off, 64);
  }
  if ((tid & 63) == 0) { rs_[tid >> 6] = s; rs2_[tid >> 6] = s2; }
  __syncthreads();
  if (tid == 0) {
    const float S = rs_[0] + rs_[1] + rs_[2] + rs_[3];
    const float S2 = rs2_[0] + rs2_[1] + rs2_[2] + rs2_[3];
    const float mean = S * (1.f / 1280.f);
    const float var = S2 * (1.f / 1280.f) - mean * mean;
    bc[0] = mean; bc[1] = rsqrtf(var + 1e-5f);
  }
  __syncthreads();
  const float mean = bc[0], rstd = bc[1];
#pragma unroll
  for (int i = 0; i < 5; ++i) {
    const int c = tid + i * 256;
    const float ln = (v[i] - mean) * rstd;
    const float y = affine ? (ln * g[c] + bv[c]) : (ln * (1.f + emb[c]) + emb[1280 + c]);
    out[row * 1280 + c] = f2bf(y);
  }
}

// v (strided ldv, h-blocked) -> vt[16][160][2048]
__global__ void transpose_v_self(const u16* __restrict__ v, int ldv,
                                 u16* __restrict__ vt) {
  __shared__ u16 t[32][33];
  const int z = blockIdx.z, b = z >> 3, hh = z & 7;
  const int s0 = blockIdx.x * 32, d0 = blockIdx.y * 32;
  const int tx = threadIdx.x, ty = threadIdx.y;
  for (int i = ty; i < 32; i += 8) {
    const int d = d0 + tx;
    t[i][tx] = (d < 160) ? v[((long)(b * 2048 + s0 + i)) * ldv + hh * 160 + d]
                         : (u16)0;
  }
  __syncthreads();
  for (int i = ty; i < 32; i += 8) {
    const int d = d0 + i;
    if (d < 160) vt[((long)z * 160 + d) * 2048 + s0 + tx] = t[tx][i];
  }
}

// cross V (ld 2560 strided) -> vct[16][160][96] (s<77 else 0)
__global__ void make_vct(const u16* __restrict__ vc,
                         u16* __restrict__ vct) {
  const int idx = blockIdx.x * 256 + threadIdx.x;
  if (idx >= 16 * 160 * 96) return;
  const int s = idx % 96;
  const int d = (idx / 96) % 160;
  const int z = idx / (96 * 160);
  const int b = z >> 3, hh = z & 7;
  u16 val = 0;
  if (s < 77) val = vc[((long)(b * 77 + s)) * 2560 + hh * 160 + d];
  vct[idx] = val;
}

__global__ __launch_bounds__(256) void softmax_self(u16* __restrict__ S) {
  const long row = blockIdx.x;
  u16* p = S + row * 2048;
  const int tid = threadIdx.x;
  const ushort8 raw = *reinterpret_cast<const ushort8*>(p + tid * 8);
  float v[8];
  float mx = -1e30f;
#pragma unroll
  for (int e = 0; e < 8; ++e) { v[e] = bf2f(raw[e]); mx = fmaxf(mx, v[e]); }
  __shared__ float red[8];
  for (int off = 32; off; off >>= 1) mx = fmaxf(mx, __shfl_down(mx, off, 64));
  if ((tid & 63) == 0) red[tid >> 6] = mx;
  __syncthreads();
  if (tid == 0) {
    float m = red[0];
    for (int w = 1; w < 4; ++w) m = fmaxf(m, red[w]);
    red[4] = m;
  }
  __syncthreads();
  mx = red[4];
  float s = 0.f;
#pragma unroll
  for (int e = 0; e < 8; ++e) { v[e] = expf(v[e] - mx); s += v[e]; }
  __syncthreads();
  for (int off = 32; off; off >>= 1) s += __shfl_down(s, off, 64);
  if ((tid & 63) == 0) red[tid >> 6] = s;
  __syncthreads();
  if (tid == 0) red[4] = red[0] + red[1] + red[2] + red[3];
  __syncthreads();
  const float inv = 1.f / red[4];
  ushort8 outv;
#pragma unroll
  for (int e = 0; e < 8; ++e) outv[e] = f2bf(v[e] * inv);
  *reinterpret_cast<ushort8*>(p + tid * 8) = outv;
}

__global__ __launch_bounds__(64) void softmax_cross(u16* __restrict__ S) {
  const long row = blockIdx.x;
  u16* p = S + row * 96;
  const int tid = threadIdx.x;
  const float v0 = (tid < 77) ? bf2f(p[tid]) : -1e30f;
  const float v1 = (tid + 64 < 77) ? bf2f(p[tid + 64]) : -1e30f;
  float mx = fmaxf(v0, v1);
  for (int off = 32; off; off >>= 1) mx = fmaxf(mx, __shfl_down(mx, off, 64));
  mx = __shfl(mx, 0, 64);
  const float e0 = (tid < 77) ? expf(v0 - mx) : 0.f;
  const float e1 = (tid + 64 < 77) ? expf(v1 - mx) : 0.f;
  float s = e0 + e1;
  for (int off = 32; off; off >>= 1) s += __shfl_down(s, off, 64);
  s = __shfl(s, 0, 64);
  const float inv = 1.f / s;
  p[tid] = (tid < 77) ? f2bf(e0 * inv) : (u16)0;
  if (tid + 64 < 96) p[tid + 64] = (tid + 64 < 77) ? f2bf(e1 * inv) : (u16)0;
}

__global__ __launch_bounds__(256) void geglu(const u16* __restrict__ ff1,
                                             u16* __restrict__ out) {
  const long gid = (long)blockIdx.x * 256 + threadIdx.x;
  if (gid >= (long)4096 * 640) return;
  const long i = gid / 640;
  const int jb = (int)(gid % 640) * 8;
  const ushort8 a = *reinterpret_cast<const ushort8*>(ff1 + i * 10240 + jb);
  const ushort8 gt = *reinterpret_cast<const ushort8*>(ff1 + i * 10240 + 5120 + jb);
  ushort8 o;
#pragma unroll
  for (int e = 0; e < 8; ++e) {
    const float av = bf2f(a[e]);
    const float gv = bf2f(gt[e]);
    const float gel = 0.5f * gv * (1.f + erff(gv * 0.7071067811865475f));
    o[e] = f2bf(av * gel);
  }
  *reinterpret_cast<ushort8*>(out + i * 5120 + jb) = o;
}

// ---------------------------------------------------------------------------
extern "C" void kernel_launch(void* const* d_in, const int* in_sizes, int n_in,
                              void* d_out, int out_size, void* d_ws, size_t ws_size,
                              hipStream_t stream) {
  (void)in_sizes; (void)n_in; (void)out_size; (void)ws_size;

  const float* hidden   = (const float*)d_in[0];
  const float* context  = (const float*)d_in[1];
  const float* ada1_tab = (const float*)d_in[2];
  const float* ada1_w   = (const float*)d_in[3];
  const float* ada1_b   = (const float*)d_in[4];
  const float* ada2_tab = (const float*)d_in[5];
  const float* ada2_w   = (const float*)d_in[6];
  const float* ada2_b   = (const float*)d_in[7];
  const float* a1_wq = (const float*)d_in[8];
  const float* a1_wk = (const float*)d_in[9];
  const float* a1_wv = (const float*)d_in[10];
  const float* a1_wo = (const float*)d_in[11];
  const float* a1_bo = (const float*)d_in[12];
  const float* a2_wq = (const float*)d_in[13];
  const float* a2_wk = (const float*)d_in[14];
  const float* a2_wv = (const float*)d_in[15];
  const float* a2_wo = (const float*)d_in[16];
  const float* a2_bo = (const float*)d_in[17];
  const float* n3_g  = (const float*)d_in[18];
  const float* n3_b  = (const float*)d_in[19];
  const float* ff_w1 = (const float*)d_in[20];
  const float* ff_b1 = (const float*)d_in[21];
  const float* ff_w2 = (const float*)d_in[22];
  const float* ff_b2 = (const float*)d_in[23];
  const int*   tstep = (const int*)d_in[24];
  float* xout = (float*)d_out;

  char* base = (char*)d_ws;
  size_t off = 0;
  auto alloc = [&](size_t bytes) -> void* {
    void* p = base + off;
    off = (off + bytes + 255) & ~(size_t)255;
    return p;
  };
  u16* wqkvT = (u16*)alloc((size_t)3 * 1280 * 1280 * 2);
  u16* wo1T = (u16*)alloc((size_t)1280 * 1280 * 2);
  u16* wq2T = (u16*)alloc((size_t)1280 * 1280 * 2);
  u16* wkv2T = (u16*)alloc((size_t)2 * 1280 * 768 * 2);
  u16* wo2T = (u16*)alloc((size_t)1280 * 1280 * 2);
  u16* w1T  = (u16*)alloc((size_t)10240 * 1280 * 2);
  u16* w2T  = (u16*)alloc((size_t)1280 * 5120 * 2);
  u16* ctxb = (u16*)alloc((size_t)154 * 768 * 2);
  float* emb1 = (float*)alloc(2560 * 4);
  float* emb2 = (float*)alloc(2560 * 4);
  u16* h   = (u16*)alloc((size_t)4096 * 1280 * 2);
  u16* qkv = (u16*)alloc((size_t)4096 * 3840 * 2);
  u16* vt  = (u16*)alloc((size_t)16 * 160 * 2048 * 2);
  u16* vct = (u16*)alloc((size_t)16 * 160 * 96 * 2);
  u16* o   = (u16*)alloc((size_t)4096 * 1280 * 2);
  u16* scores = (u16*)alloc((size_t)16 * 2048 * 2048 * 2);
  u16* qc = qkv;
  u16* kvc = o;
  u16* ffh = qkv;
  u16* ff1out = scores;

  auto g8p = [&](const u16* A, long lda, const u16* B, long ldb,
                 void* C, long ldc, const float* bias, const float* resid, long ldr,
                 int M, int N, int K, int outF32) {
    const int nbx = N >> 8;
    const int nwg = nbx * (M >> 8);
    gemm8p<<<nwg, 512, 0, stream>>>(A, lda, 0, 0, B, ldb, 0, 0,
                                    C, ldc, 0, 0, bias, resid, ldr,
                                    M, N, K, nbx, 1, outF32);
  };
  auto g64 = [&](const u16* A, long lda, long sAo, long sAi,
                 const u16* B, long ldb, long sBo, long sBi,
                 void* C, long ldc, long sCo, long sCi,
                 const float* bias, const float* resid, long ldr,
                 int M, int N, int K, int batch, int Hdiv, float alpha, int outF32) {
    const int nbx = (N + 127) >> 7;
    const int nwg = nbx * (M >> 7) * batch;
    gemm64<<<nwg, 512, 0, stream>>>(A, lda, sAo, sAi, B, ldb, sBo, sBi,
                                    C, ldc, sCo, sCi, bias, resid, ldr,
                                    M, N, K, nbx, Hdiv, alpha, outF32);
  };
  auto g32 = [&](const u16* A, long lda, long sAo, long sAi,
                 const u16* B, long ldb, long sBo, long sBi,
                 void* C, long ldc, long sCo, long sCi,
                 const float* bias, const float* resid, long ldr,
                 int M, int N, int K, int batch, int Hdiv, float alpha, int outF32) {
    const int nbx = (N + 127) >> 7;
    const int nwg = nbx * (M >> 7) * batch;
    gemm32<<<nwg, 512, 0, stream>>>(A, lda, sAo, sAi, B, ldb, sBo, sBi,
                                    C, ldc, sCo, sCi, bias, resid, ldr,
                                    M, N, K, nbx, Hdiv, alpha, outF32);
  };
  auto gemm = [&](const u16* A, long lda, long sAo, long sAi,
                  const u16* B, long ldb, long sBo, long sBi,
                  void* C, long ldc, long sCo, long sCi,
                  const float* bias, const float* resid, long ldr,
                  int M, int N, int K, int batch, int Hdiv, float alpha, int outF32) {
    dim3 g((N + 127) / 128, (M + 127) / 128, batch);
    gemm_nt<<<g, 256, 0, stream>>>(A, lda, sAo, sAi, B, ldb, sBo, sBi, C, ldc, sCo, sCi,
                                   bias, resid, ldr, M, N, K, Hdiv, alpha, outF32);
  };
  auto tconv = [&](const float* in, u16* out, int R, int C) {
    transpose_convert<<<dim3((C + 31) / 32, (R + 31) / 32), dim3(32, 8), 0, stream>>>(in, out, R, C);
  };

  // --- weight prep ---
  tconv(a1_wq, wqkvT, 1280, 1280);
  tconv(a1_wk, wqkvT + (size_t)1280 * 1280, 1280, 1280);
  tconv(a1_wv, wqkvT + (size_t)2 * 1280 * 1280, 1280, 1280);
  tconv(a1_wo, wo1T, 1280, 1280);
  tconv(a2_wq, wq2T, 1280, 1280);
  tconv(a2_wk, wkv2T, 768, 1280);
  tconv(a2_wv, wkv2T + (size_t)1280 * 768, 768, 1280);
  tconv(a2_wo, wo2T, 1280, 1280);
  tconv(ff_w1, w1T, 1280, 10240);
  tconv(ff_w2, w2T, 5120, 1280);
  {
    const long n = (long)154 * 768;
    convert_bf16<<<(int)((n + 255) / 256), 256, 0, stream>>>(context, ctxb, n);
  }
  adaln_emb<<<dim3(10, 2), 256, 0, stream>>>(ada1_tab, ada1_w, ada1_b,
                                             ada2_tab, ada2_w, ada2_b, tstep, emb1, emb2);

  const float ascale = 0.07905694150420949f; // 160^-0.5
  const long S2 = (long)2048 * 2048;
  u16* qs = qkv;
  u16* ks = qkv + 1280;
  u16* vs = qkv + 2560;

  // --- self attention ---
  ln_mod<<<4096, 256, 0, stream>>>(hidden, h, emb1, nullptr, nullptr, 0);
  g8p(h, 1280, wqkvT, 1280, qkv, 3840, nullptr, nullptr, 0, 4096, 3840, 1280, 0);
  transpose_v_self<<<dim3(64, 5, 16), dim3(32, 8), 0, stream>>>(vs, 3840, vt);
  g32(qs, 3840, (long)2048 * 3840, 160, ks, 3840, (long)2048 * 3840, 160,
      scores, 2048, 8 * S2, S2, nullptr, nullptr, 0,
      2048, 2048, 160, 16, 8, ascale, 0);
  softmax_self<<<16 * 2048, 256, 0, stream>>>(scores);
  g64(scores, 2048, 8 * S2, S2, vt, 2048, (long)8 * 160 * 2048, (long)160 * 2048,
      o, 1280, (long)2048 * 1280, 160, nullptr, nullptr, 0,
      2048, 160, 2048, 16, 8, 1.f, 0);
  g64(o, 1280, 0, 0, wo1T, 1280, 0, 0, xout, 1280, 0, 0,
      a1_bo, hidden, 1280, 4096, 1280, 1280, 1, 1, 1.f, 1);

  // --- cross attention ---
  ln_mod<<<4096, 256, 0, stream>>>(xout, h, emb2, nullptr, nullptr, 0);
  g64(h, 1280, 0, 0, wq2T, 1280, 0, 0, qc, 1280, 0, 0,
      nullptr, nullptr, 0, 4096, 1280, 1280, 1, 1, 1.f, 0);
  gemm(ctxb, 768, 0, 0, wkv2T, 768, 0, 0, kvc, 2560, 0, 0, nullptr, nullptr, 0,
       154, 2560, 768, 1, 1, 1.f, 0);
  make_vct<<<(16 * 160 * 96 + 255) / 256, 256, 0, stream>>>(kvc + 1280, vct);
  g32(qc, 1280, (long)2048 * 1280, 160, kvc, 2560, (long)77 * 2560, 160,
      scores, 96, (long)8 * 2048 * 96, (long)2048 * 96, nullptr, nullptr, 0,
      2048, 77, 160, 16, 8, ascale, 0);
  softmax_cross<<<16 * 2048, 64, 0, stream>>>(scores);
  g32(scores, 96, (long)8 * 2048 * 96, (long)2048 * 96,
      vct, 96, (long)8 * 160 * 96, (long)160 * 96,
      o, 1280, (long)2048 * 1280, 160, nullptr, nullptr, 0,
      2048, 160, 96, 16, 8, 1.f, 0);
  g64(o, 1280, 0, 0, wo2T, 1280, 0, 0, xout, 1280, 0, 0,
      a2_bo, xout, 1280, 4096, 1280, 1280, 1, 1, 1.f, 1);

  // --- feed-forward ---
  ln_mod<<<4096, 256, 0, stream>>>(xout, h, nullptr, n3_g, n3_b, 1);
  g8p(h, 1280, w1T, 1280, ff1out, 10240, ff_b1, nullptr, 0, 4096, 10240, 1280, 0);
  geglu<<<(int)(((long)4096 * 640 + 255) / 256), 256, 0, stream>>>(ff1out, ffh);
  g64(ffh, 5120, 0, 0, w2T, 5120, 0, 0, xout, 1280, 0, 0,
      ff_b2, xout, 1280, 4096, 1280, 5120, 1, 1, 1.f, 1);
}

// Round 7
// 718.778 us; speedup vs baseline: 1.1875x; 1.1875x over previous
//
#include <hip/hip_runtime.h>

typedef __attribute__((ext_vector_type(8))) unsigned short ushort8;
typedef __attribute__((ext_vector_type(4))) float f32x4;
typedef __attribute__((ext_vector_type(8))) __bf16 bf16x8;
typedef unsigned short u16;

__device__ inline unsigned short f2bf(float f) {
  unsigned u = __float_as_uint(f);
  unsigned r = (u + 0x7fffu + ((u >> 16) & 1u)) >> 16;
  return (unsigned short)r;
}
__device__ inline float bf2f(unsigned short h) {
  return __uint_as_float(((unsigned)h) << 16);
}

__device__ __forceinline__ void gload_lds16(const void* g, void* l) {
  __builtin_amdgcn_global_load_lds(
      (const __attribute__((address_space(1))) void*)g,
      (__attribute__((address_space(3))) void*)l, 16, 0, 0);
}

// block-id decomposition: XCD swizzle + grouped (8 by-rows) order
__device__ __forceinline__ void decomp_bid(int nbx, int nby, int& z, int& bx, int& by) {
  int bid = blockIdx.x;
  const int nwg = gridDim.x;
  const int q8 = nwg >> 3, r8 = nwg & 7;
  const int xcd = bid & 7, i = bid >> 3;
  bid = (xcd < r8 ? xcd * (q8 + 1) : r8 * (q8 + 1) + (xcd - r8) * q8) + i;
  const int nbb = nbx * nby;
  z = bid / nbb;
  int rem = bid - z * nbb;
  if ((nby & 7) == 0) {
    const int chunk = nbx << 3;
    const int c = rem / chunk, w = rem - c * chunk;
    bx = w >> 3;
    by = (c << 3) + (w & 7);
  } else {
    by = rem / nbx;
    bx = rem - by * nbx;
  }
}

// ---------------------------------------------------------------------------
// flash_self: fused self-attention. 1 block = (b,h) x 128-q-tile; grid 256.
// 8 waves; per wave 16 q-rows. K/V tiles of 64 kv, double-buffered, reg-staged
// (loads issued before S-phase to hide latency). Online softmax in C-layout
// registers; P staged in swizzled LDS for the PV A-operand.
// qkv: fused [4096][3840] (q|k|v); vtg: vt[16][160][2048]; o: [4096][1280].
// ---------------------------------------------------------------------------
__global__ __launch_bounds__(512, 2) void flash_self(
    const u16* __restrict__ qkv, const u16* __restrict__ vtg, u16* __restrict__ o)
{
  __shared__ __align__(128) u16 Qs[128 * 168];     // 336B rows (pad: bank-free)
  __shared__ __align__(128) u16 Ks[2][64 * 168];
  __shared__ __align__(128) u16 Vs[2][160 * 64];   // XOR-swizzled 128B rows
  __shared__ __align__(128) u16 Ps[128 * 64];      // XOR-swizzled

  const int tid = threadIdx.x;
  const int lane = tid & 63, wave = tid >> 6;
  const int r15 = lane & 15, kq = lane >> 4;
  const int z = blockIdx.x >> 4, qt = blockIdx.x & 15;
  const int b = z >> 3, hh = z & 7;
  const u16* Qg = qkv + ((long)(b * 2048 + qt * 128)) * 3840 + hh * 160;
  const u16* Kg = qkv + ((long)(b * 2048)) * 3840 + 1280 + hh * 160;
  const u16* Vg = vtg + (long)z * 160 * 2048;

  // stage Q
  for (int c = tid; c < 2560; c += 512) {
    const int r = c / 20, e = (c % 20) * 8;
    *(ushort8*)&Qs[r * 168 + e] = *(const ushort8*)(Qg + (long)r * 3840 + e);
  }
  // chunk->thread mapping for K (1280 chunks) and V (1280 chunks)
  const int c0 = tid, c1 = tid + 512, c2 = tid + 1024;
  const bool has2 = (c2 < 1280);
  const int kR0 = c0 / 20, kE0 = (c0 % 20) * 8;
  const int kR1 = c1 / 20, kE1 = (c1 % 20) * 8;
  const int kR2 = has2 ? c2 / 20 : 0, kE2 = has2 ? (c2 % 20) * 8 : 0;
  const int vR0 = c0 >> 3, vG0 = c0 & 7;
  const int vR1 = c1 >> 3, vG1 = c1 & 7;
  const int vR2 = has2 ? (c2 >> 3) : 0, vG2 = has2 ? (c2 & 7) : 0;

  // stage tile 0
  {
    ushort8 k0 = *(const ushort8*)(Kg + (long)kR0 * 3840 + kE0);
    ushort8 k1 = *(const ushort8*)(Kg + (long)kR1 * 3840 + kE1);
    ushort8 v0 = *(const ushort8*)(Vg + (long)vR0 * 2048 + vG0 * 8);
    ushort8 v1 = *(const ushort8*)(Vg + (long)vR1 * 2048 + vG1 * 8);
    *(ushort8*)&Ks[0][kR0 * 168 + kE0] = k0;
    *(ushort8*)&Ks[0][kR1 * 168 + kE1] = k1;
    *(ushort8*)&Vs[0][vR0 * 64 + ((vG0 ^ (vR0 & 7)) * 8)] = v0;
    *(ushort8*)&Vs[0][vR1 * 64 + ((vG1 ^ (vR1 & 7)) * 8)] = v1;
    if (has2) {
      ushort8 k2 = *(const ushort8*)(Kg + (long)kR2 * 3840 + kE2);
      ushort8 v2 = *(const ushort8*)(Vg + (long)vR2 * 2048 + vG2 * 8);
      *(ushort8*)&Ks[0][kR2 * 168 + kE2] = k2;
      *(ushort8*)&Vs[0][vR2 * 64 + ((vG2 ^ (vR2 & 7)) * 8)] = v2;
    }
  }
  __syncthreads();

  bf16x8 qf[5];
#pragma unroll
  for (int kf = 0; kf < 5; ++kf)
    qf[kf] = *(const bf16x8*)&Qs[(wave * 16 + r15) * 168 + kf * 32 + kq * 8];

  float m[4], l[4] = {0.f, 0.f, 0.f, 0.f};
#pragma unroll
  for (int t = 0; t < 4; ++t) m[t] = -1e30f;
  f32x4 accO[10] = {};
  const float SC = 0.07905694150420949f;   // 160^-0.5

  ushort8 kr0, kr1, kr2, vr0, vr1, vr2;

  for (int step = 0; step < 32; ++step) {
    const int cur = step & 1;
    const bool nl = step < 31;
    if (nl) {  // issue next-tile loads early; latency hides under S + softmax
      const long kv1 = (long)(step + 1) * 64;
      kr0 = *(const ushort8*)(Kg + (kv1 + kR0) * 3840 + kE0);
      kr1 = *(const ushort8*)(Kg + (kv1 + kR1) * 3840 + kE1);
      vr0 = *(const ushort8*)(Vg + (long)vR0 * 2048 + kv1 + vG0 * 8);
      vr1 = *(const ushort8*)(Vg + (long)vR1 * 2048 + kv1 + vG1 * 8);
      if (has2) {
        kr2 = *(const ushort8*)(Kg + (kv1 + kR2) * 3840 + kE2);
        vr2 = *(const ushort8*)(Vg + (long)vR2 * 2048 + kv1 + vG2 * 8);
      }
    }
    // S = Q @ K^T  (per wave: 16q x 64kv)
    f32x4 sa[4] = {};
#pragma unroll
    for (int nf = 0; nf < 4; ++nf)
#pragma unroll
      for (int kf = 0; kf < 5; ++kf) {
        const bf16x8 kfrag =
            *(const bf16x8*)&Ks[cur][(nf * 16 + r15) * 168 + kf * 32 + kq * 8];
        sa[nf] = __builtin_amdgcn_mfma_f32_16x16x32_bf16(qf[kf], kfrag, sa[nf], 0, 0, 0);
      }
    // online softmax (rows: kq*4+t; cols: r15+16nf)
    float corr[4];
#pragma unroll
    for (int t = 0; t < 4; ++t) {
      float tm = fmaxf(fmaxf(sa[0][t], sa[1][t]), fmaxf(sa[2][t], sa[3][t])) * SC;
      tm = fmaxf(tm, __shfl_xor(tm, 1, 64));
      tm = fmaxf(tm, __shfl_xor(tm, 2, 64));
      tm = fmaxf(tm, __shfl_xor(tm, 4, 64));
      tm = fmaxf(tm, __shfl_xor(tm, 8, 64));
      const float mn = fmaxf(m[t], tm);
      corr[t] = __expf(m[t] - mn);
      m[t] = mn;
    }
    const int qr0 = wave * 16 + kq * 4;
#pragma unroll
    for (int t = 0; t < 4; ++t) {
      float rs = 0.f;
      const int qr = qr0 + t;
#pragma unroll
      for (int nf = 0; nf < 4; ++nf) {
        const float p = __expf(sa[nf][t] * SC - m[t]);
        rs += p;
        const int col = r15 + nf * 16;
        Ps[qr * 64 + (((col >> 3) ^ (qr & 7)) * 8) + (col & 7)] = f2bf(p);
      }
      rs += __shfl_xor(rs, 1, 64);
      rs += __shfl_xor(rs, 2, 64);
      rs += __shfl_xor(rs, 4, 64);
      rs += __shfl_xor(rs, 8, 64);
      l[t] = l[t] * corr[t] + rs;
    }
#pragma unroll
    for (int j = 0; j < 10; ++j)
#pragma unroll
      for (int t = 0; t < 4; ++t) accO[j][t] *= corr[t];
    if (nl) {  // stage next K/V tile (loads complete by now)
      const int nxt = cur ^ 1;
      *(ushort8*)&Ks[nxt][kR0 * 168 + kE0] = kr0;
      *(ushort8*)&Ks[nxt][kR1 * 168 + kE1] = kr1;
      *(ushort8*)&Vs[nxt][vR0 * 64 + ((vG0 ^ (vR0 & 7)) * 8)] = vr0;
      *(ushort8*)&Vs[nxt][vR1 * 64 + ((vG1 ^ (vR1 & 7)) * 8)] = vr1;
      if (has2) {
        *(ushort8*)&Ks[nxt][kR2 * 168 + kE2] = kr2;
        *(ushort8*)&Vs[nxt][vR2 * 64 + ((vG2 ^ (vR2 & 7)) * 8)] = vr2;
      }
    }
    __syncthreads();
    // O += P @ V  (A=P rows q, B=Vt rows d, k=kv)
    const int arow = wave * 16 + r15;
    bf16x8 pf[2];
#pragma unroll
    for (int k2 = 0; k2 < 2; ++k2)
      pf[k2] = *(const bf16x8*)&Ps[arow * 64 + (((k2 * 4 + kq) ^ (arow & 7)) * 8)];
#pragma unroll
    for (int j = 0; j < 10; ++j)
#pragma unroll
      for (int k2 = 0; k2 < 2; ++k2) {
        const int vrow = j * 16 + r15;
        const bf16x8 vf =
            *(const bf16x8*)&Vs[cur][vrow * 64 + (((k2 * 4 + kq) ^ (vrow & 7)) * 8)];
        accO[j] = __builtin_amdgcn_mfma_f32_16x16x32_bf16(pf[k2], vf, accO[j], 0, 0, 0);
      }
    __syncthreads();
  }
  // epilogue: O /= l, write
  float inv[4];
#pragma unroll
  for (int t = 0; t < 4; ++t) inv[t] = 1.f / l[t];
  u16* orow = o + ((long)(b * 2048 + qt * 128)) * 1280 + hh * 160;
#pragma unroll
  for (int j = 0; j < 10; ++j)
#pragma unroll
    for (int t = 0; t < 4; ++t) {
      const int qr = wave * 16 + kq * 4 + t;
      orow[(long)qr * 1280 + j * 16 + r15] = f2bf(accO[j][t] * inv[t]);
    }
}

// ---------------------------------------------------------------------------
// gemm64: 128x128 tile, BK=64, 2 LDS bufs (64 KiB), 8 waves, 2 blocks/CU.
// ---------------------------------------------------------------------------
__global__ __launch_bounds__(512, 4) void gemm64(
    const u16* __restrict__ A, long lda, long sAo, long sAi,
    const u16* __restrict__ B, long ldb, long sBo, long sBi,
    void* __restrict__ C, long ldc, long sCo, long sCi,
    const float* __restrict__ bias, const float* __restrict__ resid, long ldr,
    int M, int N, int K, int nbx, int Hdiv, float alpha, int outF32)
{
  __shared__ __align__(128) char smem[65536];
  const int tid = threadIdx.x;
  const int lane = tid & 63, wave = tid >> 6;

  int z, bx, by;
  decomp_bid(nbx, M >> 7, z, bx, by);
  const int m0 = by << 7, n0 = bx << 7;
  const int zb = z / Hdiv, zh = z - zb * Hdiv;
  const u16* Ab = A + (long)zb * sAo + (long)zh * sAi;
  const u16* Bb = B + (long)zb * sBo + (long)zh * sBi;

  const int srow = tid >> 3;
  const int g8 = ((tid & 7) ^ (srow & 7)) * 8;
  long aoff[2], boff[2];
#pragma unroll
  for (int i = 0; i < 2; ++i) {
    aoff[i] = (long)(m0 + i * 64 + srow) * lda + g8;
    boff[i] = (long)(n0 + i * 64 + srow) * ldb + g8;
  }
  const int ldst = tid * 16;

  const int wm = (wave >> 2) * 64, wn = (wave & 3) * 32;
  const int r15 = lane & 15, kq = lane >> 4;
  const int offK0 = (kq ^ (lane & 7)) * 16;
  const int offK1 = ((4 + kq) ^ (lane & 7)) * 16;

  const int nt = K >> 6;

#define STAGE64(bufofs, k0)                                                       \
  do {                                                                            \
    _Pragma("unroll") for (int i = 0; i < 2; ++i)                                 \
        gload_lds16(Ab + aoff[i] + (k0), smem + (bufofs) + i * 8192 + ldst);      \
    _Pragma("unroll") for (int i = 0; i < 2; ++i)                                 \
        gload_lds16(Bb + boff[i] + (k0), smem + (bufofs) + 16384 + i * 8192 + ldst); \
  } while (0)

  STAGE64(0, 0);
  STAGE64(32768, 64);

  f32x4 acc[4][2] = {};

  for (int t = 0; t < nt; ++t) {
    const int cbuf = (t & 1) << 15;
    if (t < nt - 1) asm volatile("s_waitcnt vmcnt(4)" ::: "memory");
    else            asm volatile("s_waitcnt vmcnt(0)" ::: "memory");
    __builtin_amdgcn_s_barrier();

    bf16x8 bfr[2][2];
#pragma unroll
    for (int q = 0; q < 2; ++q) {
      if (q == 0) {
#pragma unroll
        for (int j = 0; j < 2; ++j) {
          const int bb = cbuf + 16384 + (wn + j * 16 + r15) * 128;
          bfr[j][0] = *(const bf16x8*)(smem + bb + offK0);
          bfr[j][1] = *(const bf16x8*)(smem + bb + offK1);
        }
      }
      bf16x8 af[2][2];
#pragma unroll
      for (int i2 = 0; i2 < 2; ++i2) {
        const int ab = cbuf + (wm + (q * 2 + i2) * 16 + r15) * 128;
        af[i2][0] = *(const bf16x8*)(smem + ab + offK0);
        af[i2][1] = *(const bf16x8*)(smem + ab + offK1);
      }
      __builtin_amdgcn_s_setprio(1);
#pragma unroll
      for (int kk = 0; kk < 2; ++kk)
#pragma unroll
        for (int i2 = 0; i2 < 2; ++i2)
#pragma unroll
          for (int j = 0; j < 2; ++j)
            acc[q * 2 + i2][j] = __builtin_amdgcn_mfma_f32_16x16x32_bf16(
                af[i2][kk], bfr[j][kk], acc[q * 2 + i2][j], 0, 0, 0);
      __builtin_amdgcn_s_setprio(0);
      __builtin_amdgcn_s_barrier();
    }
    if (t + 2 < nt) STAGE64(cbuf, (long)(t + 2) * 64);
  }
#undef STAGE64

  const long cbase = (long)zb * sCo + (long)zh * sCi;
  const int rb = (lane >> 4) * 4;
#pragma unroll
  for (int i = 0; i < 4; ++i) {
#pragma unroll
    for (int j = 0; j < 2; ++j) {
      const int gcol = n0 + wn + j * 16 + r15;
      if (gcol >= N) continue;
      const float bv = bias ? bias[gcol] : 0.f;
#pragma unroll
      for (int tt = 0; tt < 4; ++tt) {
        const int grow = m0 + wm + i * 16 + rb + tt;
        float val = acc[i][j][tt] * alpha + bv;
        if (resid) val += resid[(long)grow * ldr + gcol];
        const long cidx = cbase + (long)grow * ldc + gcol;
        if (outF32) ((float*)C)[cidx] = val;
        else ((u16*)C)[cidx] = f2bf(val);
      }
    }
  }
}

// ---------------------------------------------------------------------------
// gemm32: 128x128 tile, BK=32, for K%32 shapes (K=160/96).
// ---------------------------------------------------------------------------
__global__ __launch_bounds__(512, 4) void gemm32(
    const u16* __restrict__ A, long lda, long sAo, long sAi,
    const u16* __restrict__ B, long ldb, long sBo, long sBi,
    void* __restrict__ C, long ldc, long sCo, long sCi,
    const float* __restrict__ bias, const float* __restrict__ resid, long ldr,
    int M, int N, int K, int nbx, int Hdiv, float alpha, int outF32)
{
  __shared__ __align__(128) char smem[32768];
  const int tid = threadIdx.x;
  const int lane = tid & 63, wave = tid >> 6;

  int z, bx, by;
  decomp_bid(nbx, M >> 7, z, bx, by);
  const int m0 = by << 7, n0 = bx << 7;
  const int zb = z / Hdiv, zh = z - zb * Hdiv;
  const u16* Ab = A + (long)zb * sAo + (long)zh * sAi;
  const u16* Bb = B + (long)zb * sBo + (long)zh * sBi;

  const int srow = tid >> 2;
  const int g8 = ((tid & 3) ^ ((tid >> 3) & 3)) * 8;
  const long aoff = (long)(m0 + srow) * lda + g8;
  const long boff = (long)(n0 + srow) * ldb + g8;
  const int ldst = tid * 16;

  const int wm = (wave >> 2) * 64, wn = (wave & 3) * 32;
  const int r15 = lane & 15, kq = lane >> 4;
  const int goff = (kq ^ ((r15 >> 1) & 3)) * 16;

  const int nt = K >> 5;

#define STAGE32(bufofs, k0)                                                \
  do {                                                                     \
    gload_lds16(Ab + aoff + (k0), smem + (bufofs) + ldst);                 \
    gload_lds16(Bb + boff + (k0), smem + (bufofs) + 8192 + ldst);          \
  } while (0)

  STAGE32(0, 0);
  STAGE32(16384, 32);

  f32x4 acc[4][2] = {};

  for (int t = 0; t < nt; ++t) {
    const int cbuf = (t & 1) << 14;
    if (t < nt - 1) asm volatile("s_waitcnt vmcnt(2)" ::: "memory");
    else            asm volatile("s_waitcnt vmcnt(0)" ::: "memory");
    __builtin_amdgcn_s_barrier();

    bf16x8 af[4], bfr[2];
#pragma unroll
    for (int i = 0; i < 4; ++i)
      af[i] = *(const bf16x8*)(smem + cbuf + (wm + i * 16 + r15) * 64 + goff);
#pragma unroll
    for (int j = 0; j < 2; ++j)
      bfr[j] = *(const bf16x8*)(smem + cbuf + 8192 + (wn + j * 16 + r15) * 64 + goff);

    __builtin_amdgcn_s_setprio(1);
#pragma unroll
    for (int i = 0; i < 4; ++i)
#pragma unroll
      for (int j = 0; j < 2; ++j)
        acc[i][j] = __builtin_amdgcn_mfma_f32_16x16x32_bf16(af[i], bfr[j], acc[i][j], 0, 0, 0);
    __builtin_amdgcn_s_setprio(0);
    __builtin_amdgcn_s_barrier();

    if (t + 2 < nt) STAGE32(cbuf, (long)(t + 2) * 32);
  }
#undef STAGE32

  const long cbase = (long)zb * sCo + (long)zh * sCi;
  const int rb = (lane >> 4) * 4;
#pragma unroll
  for (int i = 0; i < 4; ++i) {
#pragma unroll
    for (int j = 0; j < 2; ++j) {
      const int gcol = n0 + wn + j * 16 + r15;
      if (gcol >= N) continue;
      const float bv = bias ? bias[gcol] : 0.f;
#pragma unroll
      for (int tt = 0; tt < 4; ++tt) {
        const int grow = m0 + wm + i * 16 + rb + tt;
        float val = acc[i][j][tt] * alpha + bv;
        if (resid) val += resid[(long)grow * ldr + gcol];
        const long cidx = cbase + (long)grow * ldc + gcol;
        if (outF32) ((float*)C)[cidx] = val;
        else ((u16*)C)[cidx] = f2bf(val);
      }
    }
  }
}

// ---------------------------------------------------------------------------
// Legacy 128x128 NT GEMM (M=154 ctx KV only)
// ---------------------------------------------------------------------------
__global__ __launch_bounds__(256) void gemm_nt(
    const u16* __restrict__ A, long lda, long sAo, long sAi,
    const u16* __restrict__ B, long ldb, long sBo, long sBi,
    void* __restrict__ C, long ldc, long sCo, long sCi,
    const float* __restrict__ bias,
    const float* __restrict__ resid, long ldr,
    int M, int N, int K, int Hdiv, float alpha, int outF32)
{
  __shared__ u16 As[128 * 32];
  __shared__ u16 Bs[128 * 32];
  const int tid = threadIdx.x;
  const int z = blockIdx.z;
  const int zb = z / Hdiv, zh = z % Hdiv;
  const u16* Ab = A + (long)zb * sAo + (long)zh * sAi;
  const u16* Bb = B + (long)zb * sBo + (long)zh * sBi;
  const long cbase = (long)zb * sCo + (long)zh * sCi;
  const int m0 = blockIdx.y * 128, n0 = blockIdx.x * 128;
  const int lane = tid & 63, wave = tid >> 6;
  const int wm = (wave >> 1) * 64, wn = (wave & 1) * 64;
  const int r15 = lane & 15, kb = (lane >> 4) * 8;

  f32x4 acc[4][4] = {};

  for (int k0 = 0; k0 < K; k0 += 32) {
#pragma unroll
    for (int it = 0; it < 2; ++it) {
      const int c = tid + it * 256;
      const int row = c >> 2, ko = (c & 3) * 8;
      ushort8 va = {0, 0, 0, 0, 0, 0, 0, 0};
      const int gm = m0 + row;
      if (gm < M) va = *reinterpret_cast<const ushort8*>(Ab + (long)gm * lda + k0 + ko);
      *reinterpret_cast<ushort8*>(&As[row * 32 + ko]) = va;
      ushort8 vb = {0, 0, 0, 0, 0, 0, 0, 0};
      const int gn = n0 + row;
      if (gn < N) vb = *reinterpret_cast<const ushort8*>(Bb + (long)gn * ldb + k0 + ko);
      *reinterpret_cast<ushort8*>(&Bs[row * 32 + ko]) = vb;
    }
    __syncthreads();
    bf16x8 af[4], bfr[4];
#pragma unroll
    for (int i = 0; i < 4; ++i)
      af[i] = *reinterpret_cast<const bf16x8*>(&As[(wm + i * 16 + r15) * 32 + kb]);
#pragma unroll
    for (int j = 0; j < 4; ++j)
      bfr[j] = *reinterpret_cast<const bf16x8*>(&Bs[(wn + j * 16 + r15) * 32 + kb]);
#pragma unroll
    for (int i = 0; i < 4; ++i)
#pragma unroll
      for (int j = 0; j < 4; ++j)
        acc[i][j] = __builtin_amdgcn_mfma_f32_16x16x32_bf16(af[i], bfr[j], acc[i][j], 0, 0, 0);
    __syncthreads();
  }

  const int rb = (lane >> 4) * 4;
#pragma unroll
  for (int i = 0; i < 4; ++i) {
#pragma unroll
    for (int j = 0; j < 4; ++j) {
      const int gcol = n0 + wn + j * 16 + r15;
      if (gcol >= N) continue;
#pragma unroll
      for (int t = 0; t < 4; ++t) {
        const int grow = m0 + wm + i * 16 + rb + t;
        if (grow >= M) continue;
        float val = acc[i][j][t] * alpha;
        if (bias) val += bias[gcol];
        if (resid) val += resid[(long)grow * ldr + gcol];
        const long cidx = cbase + (long)grow * ldc + gcol;
        if (outF32) ((float*)C)[cidx] = val;
        else ((u16*)C)[cidx] = f2bf(val);
      }
    }
  }
}

// ---------------------------------------------------------------------------
__global__ void transpose_convert(const float* __restrict__ in,
                                  u16* __restrict__ out, int R, int C) {
  __shared__ float tile[32][33];
  const int c0 = blockIdx.x * 32, r0 = blockIdx.y * 32;
  const int tx = threadIdx.x, ty = threadIdx.y;
  for (int i = ty; i < 32; i += 8) {
    const int r = r0 + i, c = c0 + tx;
    tile[i][tx] = (r < R && c < C) ? in[(long)r * C + c] : 0.f;
  }
  __syncthreads();
  for (int i = ty; i < 32; i += 8) {
    const int c = c0 + i, r = r0 + tx;
    if (c < C && r < R) out[(long)c * R + r] = f2bf(tile[tx][i]);
  }
}

__global__ void convert_bf16(const float* __restrict__ in,
                             u16* __restrict__ out, long n) {
  const long i = (long)blockIdx.x * 256 + threadIdx.x;
  if (i < n) out[i] = f2bf(in[i]);
}

__global__ __launch_bounds__(256) void adaln_emb(
    const float* __restrict__ t1, const float* __restrict__ w1, const float* __restrict__ b1,
    const float* __restrict__ t2, const float* __restrict__ w2, const float* __restrict__ b2,
    const int* __restrict__ tstep, float* __restrict__ e1, float* __restrict__ e2)
{
  const int which = blockIdx.y;
  const float* tb = which ? t2 : t1;
  const float* w = which ? w2 : w1;
  const float* bb = which ? b2 : b1;
  float* out = which ? e2 : e1;
  const int t = tstep[0];
  __shared__ float sil[1280];
  const int tid = threadIdx.x;
  for (int i = tid; i < 1280; i += 256) {
    const float xv = tb[(long)t * 1280 + i];
    sil[i] = xv / (1.f + expf(-xv));
  }
  __syncthreads();
  const int j = blockIdx.x * 256 + tid;
  float acc = bb[j];
  for (int k = 0; k < 1280; ++k) acc += sil[k] * w[(long)k * 2560 + j];
  out[j] = acc;
}

__global__ __launch_bounds__(256) void ln_mod(
    const float* __restrict__ x, u16* __restrict__ out,
    const float* __restrict__ emb, const float* __restrict__ g,
    const float* __restrict__ bv, int affine)
{
  const long row = blockIdx.x;
  const float* xr = x + row * 1280;
  const int tid = threadIdx.x;
  float v[5], s = 0.f, s2 = 0.f;
#pragma unroll
  for (int i = 0; i < 5; ++i) {
    const float t = xr[tid + i * 256];
    v[i] = t; s += t; s2 += t * t;
  }
  __shared__ float rs_[4], rs2_[4], bc[2];
  for (int off = 32; off; off >>= 1) {
    s += __shfl_down(s, off, 64);
    s2 += __shfl_down(s2, off, 64);
  }
  if ((tid & 63) == 0) { rs_[tid >> 6] = s; rs2_[tid >> 6] = s2; }
  __syncthreads();
  if (tid == 0) {
    const float S = rs_[0] + rs_[1] + rs_[2] + rs_[3];
    const float S2 = rs2_[0] + rs2_[1] + rs2_[2] + rs2_[3];
    const float mean = S * (1.f / 1280.f);
    const float var = S2 * (1.f / 1280.f) - mean * mean;
    bc[0] = mean; bc[1] = rsqrtf(var + 1e-5f);
  }
  __syncthreads();
  const float mean = bc[0], rstd = bc[1];
#pragma unroll
  for (int i = 0; i < 5; ++i) {
    const int c = tid + i * 256;
    const float ln = (v[i] - mean) * rstd;
    const float y = affine ? (ln * g[c] + bv[c]) : (ln * (1.f + emb[c]) + emb[1280 + c]);
    out[row * 1280 + c] = f2bf(y);
  }
}

// v (strided ldv, h-blocked) -> vt[16][160][2048]
__global__ void transpose_v_self(const u16* __restrict__ v, int ldv,
                                 u16* __restrict__ vt) {
  __shared__ u16 t[32][33];
  const int z = blockIdx.z, b = z >> 3, hh = z & 7;
  const int s0 = blockIdx.x * 32, d0 = blockIdx.y * 32;
  const int tx = threadIdx.x, ty = threadIdx.y;
  for (int i = ty; i < 32; i += 8) {
    const int d = d0 + tx;
    t[i][tx] = (d < 160) ? v[((long)(b * 2048 + s0 + i)) * ldv + hh * 160 + d]
                         : (u16)0;
  }
  __syncthreads();
  for (int i = ty; i < 32; i += 8) {
    const int d = d0 + i;
    if (d < 160) vt[((long)z * 160 + d) * 2048 + s0 + tx] = t[tx][i];
  }
}

// cross V (ld 2560 strided) -> vct[16][160][96] (s<77 else 0)
__global__ void make_vct(const u16* __restrict__ vc,
                         u16* __restrict__ vct) {
  const int idx = blockIdx.x * 256 + threadIdx.x;
  if (idx >= 16 * 160 * 96) return;
  const int s = idx % 96;
  const int d = (idx / 96) % 160;
  const int z = idx / (96 * 160);
  const int b = z >> 3, hh = z & 7;
  u16 val = 0;
  if (s < 77) val = vc[((long)(b * 77 + s)) * 2560 + hh * 160 + d];
  vct[idx] = val;
}

__global__ __launch_bounds__(64) void softmax_cross(u16* __restrict__ S) {
  const long row = blockIdx.x;
  u16* p = S + row * 96;
  const int tid = threadIdx.x;
  const float v0 = (tid < 77) ? bf2f(p[tid]) : -1e30f;
  const float v1 = (tid + 64 < 77) ? bf2f(p[tid + 64]) : -1e30f;
  float mx = fmaxf(v0, v1);
  for (int off = 32; off; off >>= 1) mx = fmaxf(mx, __shfl_down(mx, off, 64));
  mx = __shfl(mx, 0, 64);
  const float e0 = (tid < 77) ? expf(v0 - mx) : 0.f;
  const float e1 = (tid + 64 < 77) ? expf(v1 - mx) : 0.f;
  float s = e0 + e1;
  for (int off = 32; off; off >>= 1) s += __shfl_down(s, off, 64);
  s = __shfl(s, 0, 64);
  const float inv = 1.f / s;
  p[tid] = (tid < 77) ? f2bf(e0 * inv) : (u16)0;
  if (tid + 64 < 96) p[tid + 64] = (tid + 64 < 77) ? f2bf(e1 * inv) : (u16)0;
}

__global__ __launch_bounds__(256) void geglu(const u16* __restrict__ ff1,
                                             u16* __restrict__ out) {
  const long gid = (long)blockIdx.x * 256 + threadIdx.x;
  if (gid >= (long)4096 * 640) return;
  const long i = gid / 640;
  const int jb = (int)(gid % 640) * 8;
  const ushort8 a = *reinterpret_cast<const ushort8*>(ff1 + i * 10240 + jb);
  const ushort8 gt = *reinterpret_cast<const ushort8*>(ff1 + i * 10240 + 5120 + jb);
  ushort8 o;
#pragma unroll
  for (int e = 0; e < 8; ++e) {
    const float av = bf2f(a[e]);
    const float gv = bf2f(gt[e]);
    const float gel = 0.5f * gv * (1.f + erff(gv * 0.7071067811865475f));
    o[e] = f2bf(av * gel);
  }
  *reinterpret_cast<ushort8*>(out + i * 5120 + jb) = o;
}

// ---------------------------------------------------------------------------
extern "C" void kernel_launch(void* const* d_in, const int* in_sizes, int n_in,
                              void* d_out, int out_size, void* d_ws, size_t ws_size,
                              hipStream_t stream) {
  (void)in_sizes; (void)n_in; (void)out_size; (void)ws_size;

  const float* hidden   = (const float*)d_in[0];
  const float* context  = (const float*)d_in[1];
  const float* ada1_tab = (const float*)d_in[2];
  const float* ada1_w   = (const float*)d_in[3];
  const float* ada1_b   = (const float*)d_in[4];
  const float* ada2_tab = (const float*)d_in[5];
  const float* ada2_w   = (const float*)d_in[6];
  const float* ada2_b   = (const float*)d_in[7];
  const float* a1_wq = (const float*)d_in[8];
  const float* a1_wk = (const float*)d_in[9];
  const float* a1_wv = (const float*)d_in[10];
  const float* a1_wo = (const float*)d_in[11];
  const float* a1_bo = (const float*)d_in[12];
  const float* a2_wq = (const float*)d_in[13];
  const float* a2_wk = (const float*)d_in[14];
  const float* a2_wv = (const float*)d_in[15];
  const float* a2_wo = (const float*)d_in[16];
  const float* a2_bo = (const float*)d_in[17];
  const float* n3_g  = (const float*)d_in[18];
  const float* n3_b  = (const float*)d_in[19];
  const float* ff_w1 = (const float*)d_in[20];
  const float* ff_b1 = (const float*)d_in[21];
  const float* ff_w2 = (const float*)d_in[22];
  const float* ff_b2 = (const float*)d_in[23];
  const int*   tstep = (const int*)d_in[24];
  float* xout = (float*)d_out;

  char* base = (char*)d_ws;
  size_t off = 0;
  auto alloc = [&](size_t bytes) -> void* {
    void* p = base + off;
    off = (off + bytes + 255) & ~(size_t)255;
    return p;
  };
  u16* wqkvT = (u16*)alloc((size_t)3 * 1280 * 1280 * 2);
  u16* wo1T = (u16*)alloc((size_t)1280 * 1280 * 2);
  u16* wq2T = (u16*)alloc((size_t)1280 * 1280 * 2);
  u16* wkv2T = (u16*)alloc((size_t)2 * 1280 * 768 * 2);
  u16* wo2T = (u16*)alloc((size_t)1280 * 1280 * 2);
  u16* w1T  = (u16*)alloc((size_t)10240 * 1280 * 2);
  u16* w2T  = (u16*)alloc((size_t)1280 * 5120 * 2);
  u16* ctxb = (u16*)alloc((size_t)154 * 768 * 2);
  float* emb1 = (float*)alloc(2560 * 4);
  float* emb2 = (float*)alloc(2560 * 4);
  u16* h   = (u16*)alloc((size_t)4096 * 1280 * 2);
  u16* qkv = (u16*)alloc((size_t)4096 * 3840 * 2);
  u16* vt  = (u16*)alloc((size_t)16 * 160 * 2048 * 2);
  u16* vct = (u16*)alloc((size_t)16 * 160 * 96 * 2);
  u16* o   = (u16*)alloc((size_t)4096 * 1280 * 2);
  u16* scores = (u16*)alloc((size_t)16 * 2048 * 96 * 2);  // cross only now
  u16* qc = qkv;
  u16* kvc = o;
  u16* ffh = qkv;
  u16* ff1out = (u16*)alloc((size_t)4096 * 10240 * 2);

  auto g64 = [&](const u16* A, long lda, long sAo, long sAi,
                 const u16* B, long ldb, long sBo, long sBi,
                 void* C, long ldc, long sCo, long sCi,
                 const float* bias, const float* resid, long ldr,
                 int M, int N, int K, int batch, int Hdiv, float alpha, int outF32) {
    const int nbx = (N + 127) >> 7;
    const int nwg = nbx * (M >> 7) * batch;
    gemm64<<<nwg, 512, 0, stream>>>(A, lda, sAo, sAi, B, ldb, sBo, sBi,
                                    C, ldc, sCo, sCi, bias, resid, ldr,
                                    M, N, K, nbx, Hdiv, alpha, outF32);
  };
  auto g32 = [&](const u16* A, long lda, long sAo, long sAi,
                 const u16* B, long ldb, long sBo, long sBi,
                 void* C, long ldc, long sCo, long sCi,
                 const float* bias, const float* resid, long ldr,
                 int M, int N, int K, int batch, int Hdiv, float alpha, int outF32) {
    const int nbx = (N + 127) >> 7;
    const int nwg = nbx * (M >> 7) * batch;
    gemm32<<<nwg, 512, 0, stream>>>(A, lda, sAo, sAi, B, ldb, sBo, sBi,
                                    C, ldc, sCo, sCi, bias, resid, ldr,
                                    M, N, K, nbx, Hdiv, alpha, outF32);
  };
  auto gemm = [&](const u16* A, long lda, long sAo, long sAi,
                  const u16* B, long ldb, long sBo, long sBi,
                  void* C, long ldc, long sCo, long sCi,
                  const float* bias, const float* resid, long ldr,
                  int M, int N, int K, int batch, int Hdiv, float alpha, int outF32) {
    dim3 g((N + 127) / 128, (M + 127) / 128, batch);
    gemm_nt<<<g, 256, 0, stream>>>(A, lda, sAo, sAi, B, ldb, sBo, sBi, C, ldc, sCo, sCi,
                                   bias, resid, ldr, M, N, K, Hdiv, alpha, outF32);
  };
  auto tconv = [&](const float* in, u16* out, int R, int C) {
    transpose_convert<<<dim3((C + 31) / 32, (R + 31) / 32), dim3(32, 8), 0, stream>>>(in, out, R, C);
  };

  // --- weight prep ---
  tconv(a1_wq, wqkvT, 1280, 1280);
  tconv(a1_wk, wqkvT + (size_t)1280 * 1280, 1280, 1280);
  tconv(a1_wv, wqkvT + (size_t)2 * 1280 * 1280, 1280, 1280);
  tconv(a1_wo, wo1T, 1280, 1280);
  tconv(a2_wq, wq2T, 1280, 1280);
  tconv(a2_wk, wkv2T, 768, 1280);
  tconv(a2_wv, wkv2T + (size_t)1280 * 768, 768, 1280);
  tconv(a2_wo, wo2T, 1280, 1280);
  tconv(ff_w1, w1T, 1280, 10240);
  tconv(ff_w2, w2T, 5120, 1280);
  {
    const long n = (long)154 * 768;
    convert_bf16<<<(int)((n + 255) / 256), 256, 0, stream>>>(context, ctxb, n);
  }
  adaln_emb<<<dim3(10, 2), 256, 0, stream>>>(ada1_tab, ada1_w, ada1_b,
                                             ada2_tab, ada2_w, ada2_b, tstep, emb1, emb2);

  const float ascale = 0.07905694150420949f; // 160^-0.5
  u16* qc_ = qc;
  u16* vs = qkv + 2560;

  // --- self attention (fused flash) ---
  ln_mod<<<4096, 256, 0, stream>>>(hidden, h, emb1, nullptr, nullptr, 0);
  g64(h, 1280, 0, 0, wqkvT, 1280, 0, 0, qkv, 3840, 0, 0,
      nullptr, nullptr, 0, 4096, 3840, 1280, 1, 1, 1.f, 0);
  transpose_v_self<<<dim3(64, 5, 16), dim3(32, 8), 0, stream>>>(vs, 3840, vt);
  flash_self<<<256, 512, 0, stream>>>(qkv, vt, o);
  g64(o, 1280, 0, 0, wo1T, 1280, 0, 0, xout, 1280, 0, 0,
      a1_bo, hidden, 1280, 4096, 1280, 1280, 1, 1, 1.f, 1);

  // --- cross attention ---
  ln_mod<<<4096, 256, 0, stream>>>(xout, h, emb2, nullptr, nullptr, 0);
  g64(h, 1280, 0, 0, wq2T, 1280, 0, 0, qc_, 1280, 0, 0,
      nullptr, nullptr, 0, 4096, 1280, 1280, 1, 1, 1.f, 0);
  gemm(ctxb, 768, 0, 0, wkv2T, 768, 0, 0, kvc, 2560, 0, 0, nullptr, nullptr, 0,
       154, 2560, 768, 1, 1, 1.f, 0);
  make_vct<<<(16 * 160 * 96 + 255) / 256, 256, 0, stream>>>(kvc + 1280, vct);
  g32(qc_, 1280, (long)2048 * 1280, 160, kvc, 2560, (long)77 * 2560, 160,
      scores, 96, (long)8 * 2048 * 96, (long)2048 * 96, nullptr, nullptr, 0,
      2048, 77, 160, 16, 8, ascale, 0);
  softmax_cross<<<16 * 2048, 64, 0, stream>>>(scores);
  g32(scores, 96, (long)8 * 2048 * 96, (long)2048 * 96,
      vct, 96, (long)8 * 160 * 96, (long)160 * 96,
      o, 1280, (long)2048 * 1280, 160, nullptr, nullptr, 0,
      2048, 160, 96, 16, 8, 1.f, 0);
  g64(o, 1280, 0, 0, wo2T, 1280, 0, 0, xout, 1280, 0, 0,
      a2_bo, xout, 1280, 4096, 1280, 1280, 1, 1, 1.f, 1);

  // --- feed-forward ---
  ln_mod<<<4096, 256, 0, stream>>>(xout, h, nullptr, n3_g, n3_b, 1);
  g64(h, 1280, 0, 0, w1T, 1280, 0, 0, ff1out, 10240, 0, 0,
      ff_b1, nullptr, 0, 4096, 10240, 1280, 1, 1, 1.f, 0);
  geglu<<<(int)(((long)4096 * 640 + 255) / 256), 256, 0, stream>>>(ff1out, ffh);
  g64(ffh, 5120, 0, 0, w2T, 5120, 0, 0, xout, 1280, 0, 0,
      ff_b2, xout, 1280, 4096, 1280, 5120, 1, 1, 1.f, 1);
}

// Round 8
// 670.350 us; speedup vs baseline: 1.2733x; 1.0722x over previous
//
#include <hip/hip_runtime.h>

typedef __attribute__((ext_vector_type(8))) unsigned short ushort8;
typedef __attribute__((ext_vector_type(4))) float f32x4;
typedef __attribute__((ext_vector_type(8))) __bf16 bf16x8;
typedef unsigned short u16;

__device__ inline unsigned short f2bf(float f) {
  unsigned u = __float_as_uint(f);
  unsigned r = (u + 0x7fffu + ((u >> 16) & 1u)) >> 16;
  return (unsigned short)r;
}
__device__ inline float bf2f(unsigned short h) {
  return __uint_as_float(((unsigned)h) << 16);
}

__device__ __forceinline__ void gload_lds16(const void* g, void* l) {
  __builtin_amdgcn_global_load_lds(
      (const __attribute__((address_space(1))) void*)g,
      (__attribute__((address_space(3))) void*)l, 16, 0, 0);
}

// block-id decomposition: XCD swizzle + grouped (8 by-rows) order
__device__ __forceinline__ void decomp_bid(int nbx, int nby, int& z, int& bx, int& by) {
  int bid = blockIdx.x;
  const int nwg = gridDim.x;
  const int q8 = nwg >> 3, r8 = nwg & 7;
  const int xcd = bid & 7, i = bid >> 3;
  bid = (xcd < r8 ? xcd * (q8 + 1) : r8 * (q8 + 1) + (xcd - r8) * q8) + i;
  const int nbb = nbx * nby;
  z = bid / nbb;
  int rem = bid - z * nbb;
  if ((nby & 7) == 0) {
    const int chunk = nbx << 3;
    const int c = rem / chunk, w = rem - c * chunk;
    bx = w >> 3;
    by = (c << 3) + (w & 7);
  } else {
    by = rem / nbx;
    bx = rem - by * nbx;
  }
}

// ---------------------------------------------------------------------------
// flash_self: fused self-attention (verified round 7).
// ---------------------------------------------------------------------------
__global__ __launch_bounds__(512, 2) void flash_self(
    const u16* __restrict__ qkv, const u16* __restrict__ vtg, u16* __restrict__ o)
{
  __shared__ __align__(128) u16 Qs[128 * 168];
  __shared__ __align__(128) u16 Ks[2][64 * 168];
  __shared__ __align__(128) u16 Vs[2][160 * 64];
  __shared__ __align__(128) u16 Ps[128 * 64];

  const int tid = threadIdx.x;
  const int lane = tid & 63, wave = tid >> 6;
  const int r15 = lane & 15, kq = lane >> 4;
  const int z = blockIdx.x >> 4, qt = blockIdx.x & 15;
  const int b = z >> 3, hh = z & 7;
  const u16* Qg = qkv + ((long)(b * 2048 + qt * 128)) * 3840 + hh * 160;
  const u16* Kg = qkv + ((long)(b * 2048)) * 3840 + 1280 + hh * 160;
  const u16* Vg = vtg + (long)z * 160 * 2048;

  for (int c = tid; c < 2560; c += 512) {
    const int r = c / 20, e = (c % 20) * 8;
    *(ushort8*)&Qs[r * 168 + e] = *(const ushort8*)(Qg + (long)r * 3840 + e);
  }
  const int c0 = tid, c1 = tid + 512, c2 = tid + 1024;
  const bool has2 = (c2 < 1280);
  const int kR0 = c0 / 20, kE0 = (c0 % 20) * 8;
  const int kR1 = c1 / 20, kE1 = (c1 % 20) * 8;
  const int kR2 = has2 ? c2 / 20 : 0, kE2 = has2 ? (c2 % 20) * 8 : 0;
  const int vR0 = c0 >> 3, vG0 = c0 & 7;
  const int vR1 = c1 >> 3, vG1 = c1 & 7;
  const int vR2 = has2 ? (c2 >> 3) : 0, vG2 = has2 ? (c2 & 7) : 0;

  {
    ushort8 k0 = *(const ushort8*)(Kg + (long)kR0 * 3840 + kE0);
    ushort8 k1 = *(const ushort8*)(Kg + (long)kR1 * 3840 + kE1);
    ushort8 v0 = *(const ushort8*)(Vg + (long)vR0 * 2048 + vG0 * 8);
    ushort8 v1 = *(const ushort8*)(Vg + (long)vR1 * 2048 + vG1 * 8);
    *(ushort8*)&Ks[0][kR0 * 168 + kE0] = k0;
    *(ushort8*)&Ks[0][kR1 * 168 + kE1] = k1;
    *(ushort8*)&Vs[0][vR0 * 64 + ((vG0 ^ (vR0 & 7)) * 8)] = v0;
    *(ushort8*)&Vs[0][vR1 * 64 + ((vG1 ^ (vR1 & 7)) * 8)] = v1;
    if (has2) {
      ushort8 k2 = *(const ushort8*)(Kg + (long)kR2 * 3840 + kE2);
      ushort8 v2 = *(const ushort8*)(Vg + (long)vR2 * 2048 + vG2 * 8);
      *(ushort8*)&Ks[0][kR2 * 168 + kE2] = k2;
      *(ushort8*)&Vs[0][vR2 * 64 + ((vG2 ^ (vR2 & 7)) * 8)] = v2;
    }
  }
  __syncthreads();

  bf16x8 qf[5];
#pragma unroll
  for (int kf = 0; kf < 5; ++kf)
    qf[kf] = *(const bf16x8*)&Qs[(wave * 16 + r15) * 168 + kf * 32 + kq * 8];

  float m[4], l[4] = {0.f, 0.f, 0.f, 0.f};
#pragma unroll
  for (int t = 0; t < 4; ++t) m[t] = -1e30f;
  f32x4 accO[10] = {};
  const float SC = 0.07905694150420949f;

  ushort8 kr0, kr1, kr2, vr0, vr1, vr2;

  for (int step = 0; step < 32; ++step) {
    const int cur = step & 1;
    const bool nl = step < 31;
    if (nl) {
      const long kv1 = (long)(step + 1) * 64;
      kr0 = *(const ushort8*)(Kg + (kv1 + kR0) * 3840 + kE0);
      kr1 = *(const ushort8*)(Kg + (kv1 + kR1) * 3840 + kE1);
      vr0 = *(const ushort8*)(Vg + (long)vR0 * 2048 + kv1 + vG0 * 8);
      vr1 = *(const ushort8*)(Vg + (long)vR1 * 2048 + kv1 + vG1 * 8);
      if (has2) {
        kr2 = *(const ushort8*)(Kg + (kv1 + kR2) * 3840 + kE2);
        vr2 = *(const ushort8*)(Vg + (long)vR2 * 2048 + kv1 + vG2 * 8);
      }
    }
    f32x4 sa[4] = {};
#pragma unroll
    for (int nf = 0; nf < 4; ++nf)
#pragma unroll
      for (int kf = 0; kf < 5; ++kf) {
        const bf16x8 kfrag =
            *(const bf16x8*)&Ks[cur][(nf * 16 + r15) * 168 + kf * 32 + kq * 8];
        sa[nf] = __builtin_amdgcn_mfma_f32_16x16x32_bf16(qf[kf], kfrag, sa[nf], 0, 0, 0);
      }
    float corr[4];
#pragma unroll
    for (int t = 0; t < 4; ++t) {
      float tm = fmaxf(fmaxf(sa[0][t], sa[1][t]), fmaxf(sa[2][t], sa[3][t])) * SC;
      tm = fmaxf(tm, __shfl_xor(tm, 1, 64));
      tm = fmaxf(tm, __shfl_xor(tm, 2, 64));
      tm = fmaxf(tm, __shfl_xor(tm, 4, 64));
      tm = fmaxf(tm, __shfl_xor(tm, 8, 64));
      const float mn = fmaxf(m[t], tm);
      corr[t] = __expf(m[t] - mn);
      m[t] = mn;
    }
    const int qr0 = wave * 16 + kq * 4;
#pragma unroll
    for (int t = 0; t < 4; ++t) {
      float rs = 0.f;
      const int qr = qr0 + t;
#pragma unroll
      for (int nf = 0; nf < 4; ++nf) {
        const float p = __expf(sa[nf][t] * SC - m[t]);
        rs += p;
        const int col = r15 + nf * 16;
        Ps[qr * 64 + (((col >> 3) ^ (qr & 7)) * 8) + (col & 7)] = f2bf(p);
      }
      rs += __shfl_xor(rs, 1, 64);
      rs += __shfl_xor(rs, 2, 64);
      rs += __shfl_xor(rs, 4, 64);
      rs += __shfl_xor(rs, 8, 64);
      l[t] = l[t] * corr[t] + rs;
    }
#pragma unroll
    for (int j = 0; j < 10; ++j)
#pragma unroll
      for (int t = 0; t < 4; ++t) accO[j][t] *= corr[t];
    if (nl) {
      const int nxt = cur ^ 1;
      *(ushort8*)&Ks[nxt][kR0 * 168 + kE0] = kr0;
      *(ushort8*)&Ks[nxt][kR1 * 168 + kE1] = kr1;
      *(ushort8*)&Vs[nxt][vR0 * 64 + ((vG0 ^ (vR0 & 7)) * 8)] = vr0;
      *(ushort8*)&Vs[nxt][vR1 * 64 + ((vG1 ^ (vR1 & 7)) * 8)] = vr1;
      if (has2) {
        *(ushort8*)&Ks[nxt][kR2 * 168 + kE2] = kr2;
        *(ushort8*)&Vs[nxt][vR2 * 64 + ((vG2 ^ (vR2 & 7)) * 8)] = vr2;
      }
    }
    __syncthreads();
    const int arow = wave * 16 + r15;
    bf16x8 pf[2];
#pragma unroll
    for (int k2 = 0; k2 < 2; ++k2)
      pf[k2] = *(const bf16x8*)&Ps[arow * 64 + (((k2 * 4 + kq) ^ (arow & 7)) * 8)];
#pragma unroll
    for (int j = 0; j < 10; ++j)
#pragma unroll
      for (int k2 = 0; k2 < 2; ++k2) {
        const int vrow = j * 16 + r15;
        const bf16x8 vf =
            *(const bf16x8*)&Vs[cur][vrow * 64 + (((k2 * 4 + kq) ^ (vrow & 7)) * 8)];
        accO[j] = __builtin_amdgcn_mfma_f32_16x16x32_bf16(pf[k2], vf, accO[j], 0, 0, 0);
      }
    __syncthreads();
  }
  float inv[4];
#pragma unroll
  for (int t = 0; t < 4; ++t) inv[t] = 1.f / l[t];
  u16* orow = o + ((long)(b * 2048 + qt * 128)) * 1280 + hh * 160;
#pragma unroll
  for (int j = 0; j < 10; ++j)
#pragma unroll
    for (int t = 0; t < 4; ++t) {
      const int qr = wave * 16 + kq * 4 + t;
      orow[(long)qr * 1280 + j * 16 + r15] = f2bf(accO[j][t] * inv[t]);
    }
}

// ---------------------------------------------------------------------------
// flash_cross: fused cross-attention. 1 block = (b,h) x 128-q-tile; grid 256.
// Sk=77 fits one tile: single S pass, full-row softmax, single PV pass.
// q: [4096][1280] (head-blocked); kv: [154][2560] (K | V); o: [4096][1280].
// ---------------------------------------------------------------------------
__global__ __launch_bounds__(512, 1) void flash_cross(
    const u16* __restrict__ q, const u16* __restrict__ kv, u16* __restrict__ o)
{
  __shared__ __align__(128) u16 Qs[128 * 168];
  __shared__ __align__(128) u16 Ks[80 * 168];
  __shared__ __align__(128) u16 Vts[160 * 104];   // V^T, 104-pad (bank period 8)
  __shared__ __align__(128) u16 Ps[128 * 104];

  const int tid = threadIdx.x;
  const int lane = tid & 63, wave = tid >> 6;
  const int r15 = lane & 15, kq = lane >> 4;
  const int z = blockIdx.x >> 4, qt = blockIdx.x & 15;
  const int b = z >> 3, hh = z & 7;
  const u16* Qg = q + ((long)(b * 2048 + qt * 128)) * 1280 + hh * 160;
  const u16* Kg = kv + (long)b * 77 * 2560 + hh * 160;
  const u16* Vg = Kg + 1280;

  for (int c = tid; c < 2560; c += 512) {
    const int r = c / 20, e = (c % 20) * 8;
    *(ushort8*)&Qs[r * 168 + e] = *(const ushort8*)(Qg + (long)r * 1280 + e);
  }
  for (int c = tid; c < 1540; c += 512) {
    const int r = c / 20, e = (c % 20) * 8;
    *(ushort8*)&Ks[r * 168 + e] = *(const ushort8*)(Kg + (long)r * 2560 + e);
  }
  for (int c = tid; c < 3 * 168; c += 512) Ks[77 * 168 + c] = 0;
  for (int c = tid; c < 77 * 160; c += 512) {
    const int s = c / 160, d = c - s * 160;
    Vts[d * 104 + s] = Vg[(long)s * 2560 + d];
  }
  for (int c = tid; c < 160 * 27; c += 512) {
    const int d = c / 27, cc = 77 + (c - d * 27);
    Vts[d * 104 + cc] = 0;
  }
  for (int c = tid; c < 128 * 16; c += 512) {
    const int r = c >> 4, cc = 80 + (c & 15);
    Ps[r * 104 + cc] = 0;
  }
  __syncthreads();

  const float SC = 0.07905694150420949f;
  bf16x8 qf[5];
#pragma unroll
  for (int kf = 0; kf < 5; ++kf)
    qf[kf] = *(const bf16x8*)&Qs[(wave * 16 + r15) * 168 + kf * 32 + kq * 8];
  f32x4 sa[5] = {};
#pragma unroll
  for (int nf = 0; nf < 5; ++nf)
#pragma unroll
    for (int kf = 0; kf < 5; ++kf) {
      const bf16x8 kfrag = *(const bf16x8*)&Ks[(nf * 16 + r15) * 168 + kf * 32 + kq * 8];
      sa[nf] = __builtin_amdgcn_mfma_f32_16x16x32_bf16(qf[kf], kfrag, sa[nf], 0, 0, 0);
    }
  float inv[4];
#pragma unroll
  for (int t = 0; t < 4; ++t) {
    float sv[5];
    float m = -1e30f;
#pragma unroll
    for (int nf = 0; nf < 5; ++nf) {
      const int col = nf * 16 + r15;
      sv[nf] = (col < 77) ? sa[nf][t] * SC : -1e30f;
      m = fmaxf(m, sv[nf]);
    }
    m = fmaxf(m, __shfl_xor(m, 1, 64));
    m = fmaxf(m, __shfl_xor(m, 2, 64));
    m = fmaxf(m, __shfl_xor(m, 4, 64));
    m = fmaxf(m, __shfl_xor(m, 8, 64));
    const int qr = wave * 16 + kq * 4 + t;
    float rs = 0.f;
#pragma unroll
    for (int nf = 0; nf < 5; ++nf) {
      const float p = __expf(sv[nf] - m);
      rs += p;
      Ps[qr * 104 + nf * 16 + r15] = f2bf(p);
    }
    rs += __shfl_xor(rs, 1, 64);
    rs += __shfl_xor(rs, 2, 64);
    rs += __shfl_xor(rs, 4, 64);
    rs += __shfl_xor(rs, 8, 64);
    inv[t] = 1.f / rs;
  }
  __syncthreads();
  const int arow = wave * 16 + r15;
  bf16x8 pf[3];
#pragma unroll
  for (int k2 = 0; k2 < 3; ++k2)
    pf[k2] = *(const bf16x8*)&Ps[arow * 104 + k2 * 32 + kq * 8];
  f32x4 accO[10] = {};
#pragma unroll
  for (int j = 0; j < 10; ++j)
#pragma unroll
    for (int k2 = 0; k2 < 3; ++k2) {
      const bf16x8 vf = *(const bf16x8*)&Vts[(j * 16 + r15) * 104 + k2 * 32 + kq * 8];
      accO[j] = __builtin_amdgcn_mfma_f32_16x16x32_bf16(pf[k2], vf, accO[j], 0, 0, 0);
    }
  u16* orow = o + ((long)(b * 2048 + qt * 128)) * 1280 + hh * 160;
#pragma unroll
  for (int j = 0; j < 10; ++j)
#pragma unroll
    for (int t = 0; t < 4; ++t) {
      const int qr = wave * 16 + kq * 4 + t;
      orow[(long)qr * 1280 + j * 16 + r15] = f2bf(accO[j][t] * inv[t]);
    }
}

// ---------------------------------------------------------------------------
// gemm64: 128x128 tile, BK=64, 2 LDS bufs, 8 waves, 2 blocks/CU.
// geglu=1: paired-layout GEGLU epilogue (j=0 h, j=1 gate), C is [M][ldc] bf16.
// ---------------------------------------------------------------------------
__global__ __launch_bounds__(512, 4) void gemm64(
    const u16* __restrict__ A, long lda, long sAo, long sAi,
    const u16* __restrict__ B, long ldb, long sBo, long sBi,
    void* __restrict__ C, long ldc, long sCo, long sCi,
    const float* __restrict__ bias, const float* __restrict__ resid, long ldr,
    int M, int N, int K, int nbx, int Hdiv, float alpha, int outF32, int geglu)
{
  __shared__ __align__(128) char smem[65536];
  const int tid = threadIdx.x;
  const int lane = tid & 63, wave = tid >> 6;

  int z, bx, by;
  decomp_bid(nbx, M >> 7, z, bx, by);
  const int m0 = by << 7, n0 = bx << 7;
  const int zb = z / Hdiv, zh = z - zb * Hdiv;
  const u16* Ab = A + (long)zb * sAo + (long)zh * sAi;
  const u16* Bb = B + (long)zb * sBo + (long)zh * sBi;

  const int srow = tid >> 3;
  const int g8 = ((tid & 7) ^ (srow & 7)) * 8;
  long aoff[2], boff[2];
#pragma unroll
  for (int i = 0; i < 2; ++i) {
    aoff[i] = (long)(m0 + i * 64 + srow) * lda + g8;
    boff[i] = (long)(n0 + i * 64 + srow) * ldb + g8;
  }
  const int ldst = tid * 16;

  const int wm = (wave >> 2) * 64, wn = (wave & 3) * 32;
  const int r15 = lane & 15, kq = lane >> 4;
  const int offK0 = (kq ^ (lane & 7)) * 16;
  const int offK1 = ((4 + kq) ^ (lane & 7)) * 16;

  const int nt = K >> 6;

#define STAGE64(bufofs, k0)                                                       \
  do {                                                                            \
    _Pragma("unroll") for (int i = 0; i < 2; ++i)                                 \
        gload_lds16(Ab + aoff[i] + (k0), smem + (bufofs) + i * 8192 + ldst);      \
    _Pragma("unroll") for (int i = 0; i < 2; ++i)                                 \
        gload_lds16(Bb + boff[i] + (k0), smem + (bufofs) + 16384 + i * 8192 + ldst); \
  } while (0)

  STAGE64(0, 0);
  STAGE64(32768, 64);

  f32x4 acc[4][2] = {};

  for (int t = 0; t < nt; ++t) {
    const int cbuf = (t & 1) << 15;
    if (t < nt - 1) asm volatile("s_waitcnt vmcnt(4)" ::: "memory");
    else            asm volatile("s_waitcnt vmcnt(0)" ::: "memory");
    __builtin_amdgcn_s_barrier();

    bf16x8 bfr[2][2];
#pragma unroll
    for (int q = 0; q < 2; ++q) {
      if (q == 0) {
#pragma unroll
        for (int j = 0; j < 2; ++j) {
          const int bb = cbuf + 16384 + (wn + j * 16 + r15) * 128;
          bfr[j][0] = *(const bf16x8*)(smem + bb + offK0);
          bfr[j][1] = *(const bf16x8*)(smem + bb + offK1);
        }
      }
      bf16x8 af[2][2];
#pragma unroll
      for (int i2 = 0; i2 < 2; ++i2) {
        const int ab = cbuf + (wm + (q * 2 + i2) * 16 + r15) * 128;
        af[i2][0] = *(const bf16x8*)(smem + ab + offK0);
        af[i2][1] = *(const bf16x8*)(smem + ab + offK1);
      }
      __builtin_amdgcn_s_setprio(1);
#pragma unroll
      for (int kk = 0; kk < 2; ++kk)
#pragma unroll
        for (int i2 = 0; i2 < 2; ++i2)
#pragma unroll
          for (int j = 0; j < 2; ++j)
            acc[q * 2 + i2][j] = __builtin_amdgcn_mfma_f32_16x16x32_bf16(
                af[i2][kk], bfr[j][kk], acc[q * 2 + i2][j], 0, 0, 0);
      __builtin_amdgcn_s_setprio(0);
      __builtin_amdgcn_s_barrier();
    }
    if (t + 2 < nt) STAGE64(cbuf, (long)(t + 2) * 64);
  }
#undef STAGE64

  const long cbase = (long)zb * sCo + (long)zh * sCi;
  const int rb = (lane >> 4) * 4;
  if (geglu) {
    const int cH = n0 + wn + r15;
    const float bh = bias[cH], bg = bias[cH + 16];
    const int ocol = ((n0 + wn) >> 1) + r15;
#pragma unroll
    for (int i = 0; i < 4; ++i) {
#pragma unroll
      for (int tt = 0; tt < 4; ++tt) {
        const int grow = m0 + wm + i * 16 + rb + tt;
        const float hv = acc[i][0][tt] + bh;
        const float gv = acc[i][1][tt] + bg;
        const float gel = 0.5f * gv * (1.f + erff(gv * 0.7071067811865475f));
        ((u16*)C)[(long)grow * ldc + ocol] = f2bf(hv * gel);
      }
    }
    return;
  }
#pragma unroll
  for (int i = 0; i < 4; ++i) {
#pragma unroll
    for (int j = 0; j < 2; ++j) {
      const int gcol = n0 + wn + j * 16 + r15;
      if (gcol >= N) continue;
      const float bv = bias ? bias[gcol] : 0.f;
#pragma unroll
      for (int tt = 0; tt < 4; ++tt) {
        const int grow = m0 + wm + i * 16 + rb + tt;
        float val = acc[i][j][tt] * alpha + bv;
        if (resid) val += resid[(long)grow * ldr + gcol];
        const long cidx = cbase + (long)grow * ldc + gcol;
        if (outF32) ((float*)C)[cidx] = val;
        else ((u16*)C)[cidx] = f2bf(val);
      }
    }
  }
}

// ---------------------------------------------------------------------------
// Legacy 128x128 NT GEMM (M=154 ctx KV only)
// ---------------------------------------------------------------------------
__global__ __launch_bounds__(256) void gemm_nt(
    const u16* __restrict__ A, long lda, long sAo, long sAi,
    const u16* __restrict__ B, long ldb, long sBo, long sBi,
    void* __restrict__ C, long ldc, long sCo, long sCi,
    const float* __restrict__ bias,
    const float* __restrict__ resid, long ldr,
    int M, int N, int K, int Hdiv, float alpha, int outF32)
{
  __shared__ u16 As[128 * 32];
  __shared__ u16 Bs[128 * 32];
  const int tid = threadIdx.x;
  const int z = blockIdx.z;
  const int zb = z / Hdiv, zh = z % Hdiv;
  const u16* Ab = A + (long)zb * sAo + (long)zh * sAi;
  const u16* Bb = B + (long)zb * sBo + (long)zh * sBi;
  const long cbase = (long)zb * sCo + (long)zh * sCi;
  const int m0 = blockIdx.y * 128, n0 = blockIdx.x * 128;
  const int lane = tid & 63, wave = tid >> 6;
  const int wm = (wave >> 1) * 64, wn = (wave & 1) * 64;
  const int r15 = lane & 15, kb = (lane >> 4) * 8;

  f32x4 acc[4][4] = {};

  for (int k0 = 0; k0 < K; k0 += 32) {
#pragma unroll
    for (int it = 0; it < 2; ++it) {
      const int c = tid + it * 256;
      const int row = c >> 2, ko = (c & 3) * 8;
      ushort8 va = {0, 0, 0, 0, 0, 0, 0, 0};
      const int gm = m0 + row;
      if (gm < M) va = *reinterpret_cast<const ushort8*>(Ab + (long)gm * lda + k0 + ko);
      *reinterpret_cast<ushort8*>(&As[row * 32 + ko]) = va;
      ushort8 vb = {0, 0, 0, 0, 0, 0, 0, 0};
      const int gn = n0 + row;
      if (gn < N) vb = *reinterpret_cast<const ushort8*>(Bb + (long)gn * ldb + k0 + ko);
      *reinterpret_cast<ushort8*>(&Bs[row * 32 + ko]) = vb;
    }
    __syncthreads();
    bf16x8 af[4], bfr[4];
#pragma unroll
    for (int i = 0; i < 4; ++i)
      af[i] = *reinterpret_cast<const bf16x8*>(&As[(wm + i * 16 + r15) * 32 + kb]);
#pragma unroll
    for (int j = 0; j < 4; ++j)
      bfr[j] = *reinterpret_cast<const bf16x8*>(&Bs[(wn + j * 16 + r15) * 32 + kb]);
#pragma unroll
    for (int i = 0; i < 4; ++i)
#pragma unroll
      for (int j = 0; j < 4; ++j)
        acc[i][j] = __builtin_amdgcn_mfma_f32_16x16x32_bf16(af[i], bfr[j], acc[i][j], 0, 0, 0);
    __syncthreads();
  }

  const int rb = (lane >> 4) * 4;
#pragma unroll
  for (int i = 0; i < 4; ++i) {
#pragma unroll
    for (int j = 0; j < 4; ++j) {
      const int gcol = n0 + wn + j * 16 + r15;
      if (gcol >= N) continue;
#pragma unroll
      for (int t = 0; t < 4; ++t) {
        const int grow = m0 + wm + i * 16 + rb + t;
        if (grow >= M) continue;
        float val = acc[i][j][t] * alpha;
        if (bias) val += bias[gcol];
        if (resid) val += resid[(long)grow * ldr + gcol];
        const long cidx = cbase + (long)grow * ldc + gcol;
        if (outF32) ((float*)C)[cidx] = val;
        else ((u16*)C)[cidx] = f2bf(val);
      }
    }
  }
}

// ---------------------------------------------------------------------------
__global__ void transpose_convert(const float* __restrict__ in,
                                  u16* __restrict__ out, int R, int C) {
  __shared__ float tile[32][33];
  const int c0 = blockIdx.x * 32, r0 = blockIdx.y * 32;
  const int tx = threadIdx.x, ty = threadIdx.y;
  for (int i = ty; i < 32; i += 8) {
    const int r = r0 + i, c = c0 + tx;
    tile[i][tx] = (r < R && c < C) ? in[(long)r * C + c] : 0.f;
  }
  __syncthreads();
  for (int i = ty; i < 32; i += 8) {
    const int c = c0 + i, r = r0 + tx;
    if (c < C && r < R) out[(long)c * R + r] = f2bf(tile[tx][i]);
  }
}

// w1 [1280][10240] f32 -> w1Tp [10240][1280] bf16, rows permuted for GEGLU
// pairing: out row r (w=r>>5, s=r&31): src col = s<16 ? w*16+s : 5120+w*16+s-16
__global__ void tconv_ff1(const float* __restrict__ in, u16* __restrict__ out) {
  __shared__ float tile[32][33];
  const int r0 = blockIdx.y * 32;
  const int k0 = blockIdx.x * 32;
  const int w = r0 >> 5;
  const int tx = threadIdx.x, ty = threadIdx.y;
  const int src = (tx < 16) ? (w * 16 + tx) : (5120 + w * 16 + tx - 16);
  for (int i = ty; i < 32; i += 8)
    tile[i][tx] = in[(long)(k0 + i) * 10240 + src];
  __syncthreads();
  for (int i = ty; i < 32; i += 8)
    out[(long)(r0 + i) * 1280 + k0 + tx] = f2bf(tile[tx][i]);
}

__global__ void perm_b1(const float* __restrict__ b, float* __restrict__ bp) {
  const int r = blockIdx.x * 256 + threadIdx.x;
  if (r >= 10240) return;
  const int w = r >> 5, s = r & 31;
  bp[r] = b[(s < 16) ? (w * 16 + s) : (5120 + w * 16 + s - 16)];
}

__global__ void convert_bf16(const float* __restrict__ in,
                             u16* __restrict__ out, long n) {
  const long i = (long)blockIdx.x * 256 + threadIdx.x;
  if (i < n) out[i] = f2bf(in[i]);
}

__global__ __launch_bounds__(256) void adaln_emb(
    const float* __restrict__ t1, const float* __restrict__ w1, const float* __restrict__ b1,
    const float* __restrict__ t2, const float* __restrict__ w2, const float* __restrict__ b2,
    const int* __restrict__ tstep, float* __restrict__ e1, float* __restrict__ e2)
{
  const int which = blockIdx.y;
  const float* tb = which ? t2 : t1;
  const float* w = which ? w2 : w1;
  const float* bb = which ? b2 : b1;
  float* out = which ? e2 : e1;
  const int t = tstep[0];
  __shared__ float sil[1280];
  const int tid = threadIdx.x;
  for (int i = tid; i < 1280; i += 256) {
    const float xv = tb[(long)t * 1280 + i];
    sil[i] = xv / (1.f + expf(-xv));
  }
  __syncthreads();
  const int j = blockIdx.x * 256 + tid;
  float acc = bb[j];
  for (int k = 0; k < 1280; ++k) acc += sil[k] * w[(long)k * 2560 + j];
  out[j] = acc;
}

__global__ __launch_bounds__(256) void ln_mod(
    const float* __restrict__ x, u16* __restrict__ out,
    const float* __restrict__ emb, const float* __restrict__ g,
    const float* __restrict__ bv, int affine)
{
  const long row = blockIdx.x;
  const float* xr = x + row * 1280;
  const int tid = threadIdx.x;
  float v[5], s = 0.f, s2 = 0.f;
#pragma unroll
  for (int i = 0; i < 5; ++i) {
    const float t = xr[tid + i * 256];
    v[i] = t; s += t; s2 += t * t;
  }
  __shared__ float rs_[4], rs2_[4], bc[2];
  for (int off = 32; off; off >>= 1) {
    s += __shfl_down(s, off, 64);
    s2 += __shfl_down(s2, off, 64);
  }
  if ((tid & 63) == 0) { rs_[tid >> 6] = s; rs2_[tid >> 6] = s2; }
  __syncthreads();
  if (tid == 0) {
    const float S = rs_[0] + rs_[1] + rs_[2] + rs_[3];
    const float S2 = rs2_[0] + rs2_[1] + rs2_[2] + rs2_[3];
    const float mean = S * (1.f / 1280.f);
    const float var = S2 * (1.f / 1280.f) - mean * mean;
    bc[0] = mean; bc[1] = rsqrtf(var + 1e-5f);
  }
  __syncthreads();
  const float mean = bc[0], rstd = bc[1];
#pragma unroll
  for (int i = 0; i < 5; ++i) {
    const int c = tid + i * 256;
    const float ln = (v[i] - mean) * rstd;
    const float y = affine ? (ln * g[c] + bv[c]) : (ln * (1.f + emb[c]) + emb[1280 + c]);
    out[row * 1280 + c] = f2bf(y);
  }
}

// v (strided ldv, h-blocked) -> vt[16][160][2048]
__global__ void transpose_v_self(const u16* __restrict__ v, int ldv,
                                 u16* __restrict__ vt) {
  __shared__ u16 t[32][33];
  const int z = blockIdx.z, b = z >> 3, hh = z & 7;
  const int s0 = blockIdx.x * 32, d0 = blockIdx.y * 32;
  const int tx = threadIdx.x, ty = threadIdx.y;
  for (int i = ty; i < 32; i += 8) {
    const int d = d0 + tx;
    t[i][tx] = (d < 160) ? v[((long)(b * 2048 + s0 + i)) * ldv + hh * 160 + d]
                         : (u16)0;
  }
  __syncthreads();
  for (int i = ty; i < 32; i += 8) {
    const int d = d0 + i;
    if (d < 160) vt[((long)z * 160 + d) * 2048 + s0 + tx] = t[tx][i];
  }
}

// ---------------------------------------------------------------------------
extern "C" void kernel_launch(void* const* d_in, const int* in_sizes, int n_in,
                              void* d_out, int out_size, void* d_ws, size_t ws_size,
                              hipStream_t stream) {
  (void)in_sizes; (void)n_in; (void)out_size; (void)ws_size;

  const float* hidden   = (const float*)d_in[0];
  const float* context  = (const float*)d_in[1];
  const float* ada1_tab = (const float*)d_in[2];
  const float* ada1_w   = (const float*)d_in[3];
  const float* ada1_b   = (const float*)d_in[4];
  const float* ada2_tab = (const float*)d_in[5];
  const float* ada2_w   = (const float*)d_in[6];
  const float* ada2_b   = (const float*)d_in[7];
  const float* a1_wq = (const float*)d_in[8];
  const float* a1_wk = (const float*)d_in[9];
  const float* a1_wv = (const float*)d_in[10];
  const float* a1_wo = (const float*)d_in[11];
  const float* a1_bo = (const float*)d_in[12];
  const float* a2_wq = (const float*)d_in[13];
  const float* a2_wk = (const float*)d_in[14];
  const float* a2_wv = (const float*)d_in[15];
  const float* a2_wo = (const float*)d_in[16];
  const float* a2_bo = (const float*)d_in[17];
  const float* n3_g  = (const float*)d_in[18];
  const float* n3_b  = (const float*)d_in[19];
  const float* ff_w1 = (const float*)d_in[20];
  const float* ff_b1 = (const float*)d_in[21];
  const float* ff_w2 = (const float*)d_in[22];
  const float* ff_b2 = (const float*)d_in[23];
  const int*   tstep = (const int*)d_in[24];
  float* xout = (float*)d_out;

  char* base = (char*)d_ws;
  size_t off = 0;
  auto alloc = [&](size_t bytes) -> void* {
    void* p = base + off;
    off = (off + bytes + 255) & ~(size_t)255;
    return p;
  };
  u16* wqkvT = (u16*)alloc((size_t)3 * 1280 * 1280 * 2);
  u16* wo1T = (u16*)alloc((size_t)1280 * 1280 * 2);
  u16* wq2T = (u16*)alloc((size_t)1280 * 1280 * 2);
  u16* wkv2T = (u16*)alloc((size_t)2 * 1280 * 768 * 2);
  u16* wo2T = (u16*)alloc((size_t)1280 * 1280 * 2);
  u16* w1Tp = (u16*)alloc((size_t)10240 * 1280 * 2);
  u16* w2T  = (u16*)alloc((size_t)1280 * 5120 * 2);
  u16* ctxb = (u16*)alloc((size_t)154 * 768 * 2);
  float* emb1 = (float*)alloc(2560 * 4);
  float* emb2 = (float*)alloc(2560 * 4);
  float* b1p  = (float*)alloc(10240 * 4);
  u16* h   = (u16*)alloc((size_t)4096 * 1280 * 2);
  u16* qkv = (u16*)alloc((size_t)4096 * 3840 * 2);
  u16* vt  = (u16*)alloc((size_t)16 * 160 * 2048 * 2);
  u16* o   = (u16*)alloc((size_t)4096 * 1280 * 2);
  u16* kvx = (u16*)alloc((size_t)154 * 2560 * 2);
  u16* qc = qkv;
  u16* ffh = qkv;   // [4096][5120] over qkv+vt (31.5+10.5 MB >= 42 MB)

  auto g64 = [&](const u16* A, long lda, long sAo, long sAi,
                 const u16* B, long ldb, long sBo, long sBi,
                 void* C, long ldc, long sCo, long sCi,
                 const float* bias, const float* resid, long ldr,
                 int M, int N, int K, int batch, int Hdiv, float alpha,
                 int outF32, int geglu) {
    const int nbx = (N + 127) >> 7;
    const int nwg = nbx * (M >> 7) * batch;
    gemm64<<<nwg, 512, 0, stream>>>(A, lda, sAo, sAi, B, ldb, sBo, sBi,
                                    C, ldc, sCo, sCi, bias, resid, ldr,
                                    M, N, K, nbx, Hdiv, alpha, outF32, geglu);
  };
  auto gemm = [&](const u16* A, long lda, long sAo, long sAi,
                  const u16* B, long ldb, long sBo, long sBi,
                  void* C, long ldc, long sCo, long sCi,
                  const float* bias, const float* resid, long ldr,
                  int M, int N, int K, int batch, int Hdiv, float alpha, int outF32) {
    dim3 g((N + 127) / 128, (M + 127) / 128, batch);
    gemm_nt<<<g, 256, 0, stream>>>(A, lda, sAo, sAi, B, ldb, sBo, sBi, C, ldc, sCo, sCi,
                                   bias, resid, ldr, M, N, K, Hdiv, alpha, outF32);
  };
  auto tconv = [&](const float* in, u16* out, int R, int C) {
    transpose_convert<<<dim3((C + 31) / 32, (R + 31) / 32), dim3(32, 8), 0, stream>>>(in, out, R, C);
  };

  // --- weight prep ---
  tconv(a1_wq, wqkvT, 1280, 1280);
  tconv(a1_wk, wqkvT + (size_t)1280 * 1280, 1280, 1280);
  tconv(a1_wv, wqkvT + (size_t)2 * 1280 * 1280, 1280, 1280);
  tconv(a1_wo, wo1T, 1280, 1280);
  tconv(a2_wq, wq2T, 1280, 1280);
  tconv(a2_wk, wkv2T, 768, 1280);
  tconv(a2_wv, wkv2T + (size_t)1280 * 768, 768, 1280);
  tconv(a2_wo, wo2T, 1280, 1280);
  tconv_ff1<<<dim3(40, 320), dim3(32, 8), 0, stream>>>(ff_w1, w1Tp);
  perm_b1<<<40, 256, 0, stream>>>(ff_b1, b1p);
  tconv(ff_w2, w2T, 5120, 1280);
  {
    const long n = (long)154 * 768;
    convert_bf16<<<(int)((n + 255) / 256), 256, 0, stream>>>(context, ctxb, n);
  }
  adaln_emb<<<dim3(10, 2), 256, 0, stream>>>(ada1_tab, ada1_w, ada1_b,
                                             ada2_tab, ada2_w, ada2_b, tstep, emb1, emb2);

  u16* vs = qkv + 2560;

  // --- self attention (fused flash) ---
  ln_mod<<<4096, 256, 0, stream>>>(hidden, h, emb1, nullptr, nullptr, 0);
  g64(h, 1280, 0, 0, wqkvT, 1280, 0, 0, qkv, 3840, 0, 0,
      nullptr, nullptr, 0, 4096, 3840, 1280, 1, 1, 1.f, 0, 0);
  transpose_v_self<<<dim3(64, 5, 16), dim3(32, 8), 0, stream>>>(vs, 3840, vt);
  flash_self<<<256, 512, 0, stream>>>(qkv, vt, o);
  g64(o, 1280, 0, 0, wo1T, 1280, 0, 0, xout, 1280, 0, 0,
      a1_bo, hidden, 1280, 4096, 1280, 1280, 1, 1, 1.f, 1, 0);

  // --- cross attention (fused flash) ---
  ln_mod<<<4096, 256, 0, stream>>>(xout, h, emb2, nullptr, nullptr, 0);
  g64(h, 1280, 0, 0, wq2T, 1280, 0, 0, qc, 1280, 0, 0,
      nullptr, nullptr, 0, 4096, 1280, 1280, 1, 1, 1.f, 0, 0);
  gemm(ctxb, 768, 0, 0, wkv2T, 768, 0, 0, kvx, 2560, 0, 0, nullptr, nullptr, 0,
       154, 2560, 768, 1, 1, 1.f, 0);
  flash_cross<<<256, 512, 0, stream>>>(qc, kvx, o);
  g64(o, 1280, 0, 0, wo2T, 1280, 0, 0, xout, 1280, 0, 0,
      a2_bo, xout, 1280, 4096, 1280, 1280, 1, 1, 1.f, 1, 0);

  // --- feed-forward (GEGLU fused into FF1 epilogue) ---
  ln_mod<<<4096, 256, 0, stream>>>(xout, h, nullptr, n3_g, n3_b, 1);
  g64(h, 1280, 0, 0, w1Tp, 1280, 0, 0, ffh, 5120, 0, 0,
      b1p, nullptr, 0, 4096, 10240, 1280, 1, 1, 1.f, 0, 1);
  g64(ffh, 5120, 0, 0, w2T, 5120, 0, 0, xout, 1280, 0, 0,
      ff_b2, xout, 1280, 4096, 1280, 5120, 1, 1, 1.f, 1, 0);
}